// Round 14
// baseline (281.934 us; speedup 1.0000x reference)
//
#include <hip/hip_runtime.h>
#include <hip/hip_bf16.h>
#include <math.h>

using bf16 = __hip_bfloat16;

#define L_SEQ   2048
#define DMODEL  256
#define DINNER  1024
#define DSTATE  128
#define NH      16
#define HD      64
#define CONVDIM 1280
#define DPROJ   2320
#define NCHK    8
#define CT      256
#define BATCH   2
#define M_TOT   (BATCH*L_SEQ)

#define ACS_N   (BATCH*NH*NCHK*CT)
#define ST_N    ((size_t)BATCH*NCHK*NH*HD*DSTATE)
#define CB_N    ((size_t)BATCH*NCHK*CT*CT)

typedef __bf16 bf16x8_t __attribute__((ext_vector_type(8)));
typedef __bf16 bf16x4_t __attribute__((ext_vector_type(4)));
typedef float  f32x4_t  __attribute__((ext_vector_type(4)));

__device__ __forceinline__ float tof(bf16 v){ return __bfloat162float(v); }
__device__ __forceinline__ bf16  tob(float v){ return __float2bfloat16(v); }
__device__ __forceinline__ float expdec(float a){ return __expf(fminf(a, 0.f)); }

// ---------------- front mega-kernel: weight casts + owt/psum prep + batch stats --
__global__ __launch_bounds__(256) void k_front(
    const float* __restrict__ iw0, const float* __restrict__ iw1, const float* __restrict__ pw,
    bf16* __restrict__ inw_bf, bf16* __restrict__ projw_bf,
    const float* __restrict__ ow0, const float* __restrict__ ow1,
    bf16* __restrict__ owt, bf16* __restrict__ psum,
    const float* __restrict__ x, float2* __restrict__ pbuf){
  __shared__ __bf16 tile[64][65];
  __shared__ float sh[8];
  int bz = blockIdx.x, t = threadIdx.x;
  if (bz < 1160){
    int dir = bz >= 580; int sub = dir ? bz - 580 : bz;
    const float* src = dir ? iw1 : iw0;
    bf16* dst = inw_bf + (size_t)dir*DPROJ*DMODEL;
    int i = (sub*256 + t)*4;
    float4 v = *(const float4*)(src + i);
    dst[i]   = tob(v.x); dst[i+1] = tob(v.y);
    dst[i+2] = tob(v.z); dst[i+3] = tob(v.w);
  } else if (bz < 1288){
    int i = ((bz-1160)*256 + t)*4;
    float4 v = *(const float4*)(pw + i);
    projw_bf[i]   = tob(v.x); projw_bf[i+1] = tob(v.y);
    projw_bf[i+2] = tob(v.z); projw_bf[i+3] = tob(v.w);
  } else if (bz < 1416){
    int sub = bz - 1288;
    int dir = sub >> 6; int tid = sub & 63;
    int k0 = (tid >> 2)*64, j0 = (tid & 3)*64;
    const float* src = dir ? ow1 : ow0;
    bf16* dst = owt + (size_t)dir*DINNER*DMODEL;
    #pragma unroll
    for (int it = 0; it < 2; ++it){
      int idx = t + it*256; int jj = idx >> 3; int k8 = (idx & 7)*8;
      float4 va = *(const float4*)&src[(size_t)(j0+jj)*DINNER + k0 + k8];
      float4 vb = *(const float4*)&src[(size_t)(j0+jj)*DINNER + k0 + k8 + 4];
      tile[k8+0][jj] = (__bf16)va.x; tile[k8+1][jj] = (__bf16)va.y;
      tile[k8+2][jj] = (__bf16)va.z; tile[k8+3][jj] = (__bf16)va.w;
      tile[k8+4][jj] = (__bf16)vb.x; tile[k8+5][jj] = (__bf16)vb.y;
      tile[k8+6][jj] = (__bf16)vb.z; tile[k8+7][jj] = (__bf16)vb.w;
    }
    __syncthreads();
    #pragma unroll
    for (int it = 0; it < 2; ++it){
      int idx = t + it*256; int kr = idx >> 3; int j8 = (idx & 7)*8;
      bf16x8_t o;
      #pragma unroll
      for (int i = 0; i < 8; ++i) o[i] = tile[kr][j8+i];
      *(bf16x8_t*)&dst[(size_t)(k0+kr)*DMODEL + j0 + j8] = o;
    }
  } else if (bz < 1448){
    int i = ((bz - 1416)*256 + t)*8;
    int j = i & 255;
    const float* row = pw + (size_t)(i >> 8)*(2*DMODEL);
    bf16x8_t o;
    #pragma unroll
    for (int c = 0; c < 8; ++c) o[c] = (__bf16)(row[j+c] + row[256+j+c]);
    *(bf16x8_t*)&psum[i] = o;
  } else {
    int sub = bz - 1448;
    int blk = sub & 127, b = sub >> 7;
    const float4* p = (const float4*)(x + (size_t)b*(DMODEL*L_SEQ) + (size_t)blk*4096);
    float s = 0.f, ss = 0.f;
    #pragma unroll
    for (int k = 0; k < 4; ++k){
      float4 v = p[t + k*256];
      s  += v.x + v.y + v.z + v.w;
      ss += v.x*v.x + v.y*v.y + v.z*v.z + v.w*v.w;
    }
    for (int o = 32; o > 0; o >>= 1){ s += __shfl_down(s, o, 64); ss += __shfl_down(ss, o, 64); }
    if ((t & 63) == 0){ sh[(t>>6)*2] = s; sh[(t>>6)*2+1] = ss; }
    __syncthreads();
    if (t == 0){
      s  = sh[0]+sh[2]+sh[4]+sh[6];
      ss = sh[1]+sh[3]+sh[5]+sh[7];
      pbuf[b*128 + blk] = make_float2(s, ss);
    }
  }
}

// ---------------- merged: W = P@owt (blocks 0-63) + GroupNorm/transpose (64-319) -
__global__ __launch_bounds__(256) void k_wt(const bf16* __restrict__ P, const bf16* __restrict__ owt,
                                            bf16* __restrict__ W,
                                            const float* __restrict__ x, const float* __restrict__ gw,
                                            const float* __restrict__ gb, const float2* __restrict__ pbuf,
                                            bf16* __restrict__ t_out){
  __shared__ __align__(16) bf16 lds[2][(128+64)*40];
  __shared__ float tile[64][65];
  __shared__ float sh[4];
  int bz6 = blockIdx.x;
  int t = threadIdx.x;
  if (bz6 < 64){
    int dir = bz6 & 1;
    int m0 = (bz6 >> 5)*128, n0 = ((bz6 >> 1) & 15)*64;
    int wave = t >> 6, lane = t & 63;
    int wm = (wave & 1)*64, wn = (wave >> 1)*32;
    int lrow = lane & 15, quad = lane >> 4, lk8 = quad*8;

    int r0 = t >> 2, o0 = (t & 3)*8;
    int r1 = r0 + 64;
    const bf16* Ap0 = P + (size_t)(m0 + r0)*(2*DMODEL) + dir*DMODEL + o0;
    const bf16* Ap1 = P + (size_t)(m0 + r1)*(2*DMODEL) + dir*DMODEL + o0;
    const bf16* Bp  = owt + (size_t)dir*DINNER*DMODEL + (size_t)(n0 + r0)*DMODEL + o0;

    f32x4_t acc[4][2];
    #pragma unroll
    for (int i = 0; i < 4; ++i){ acc[i][0] = (f32x4_t){0,0,0,0}; acc[i][1] = (f32x4_t){0,0,0,0}; }

    int nit = DMODEL >> 5;  // 8
    uint4 a0 = *(const uint4*)Ap0;
    uint4 a1 = *(const uint4*)Ap1;
    uint4 b0 = *(const uint4*)Bp;
    int st = 0;
    *(uint4*)&lds[0][r0*40 + o0] = a0;
    *(uint4*)&lds[0][r1*40 + o0] = a1;
    *(uint4*)&lds[0][(128 + r0)*40 + o0] = b0;
    __syncthreads();
    for (int it = 0; it < nit; ++it){
      bool more = (it+1 < nit);
      if (more){
        int kk = (it+1) << 5;
        a0 = *(const uint4*)(Ap0 + kk);
        a1 = *(const uint4*)(Ap1 + kk);
        b0 = *(const uint4*)(Bp + kk);
      }
      const bf16* cs = lds[st];
      bf16x8_t af[4], bfr[2];
      #pragma unroll
      for (int mi = 0; mi < 4; ++mi) af[mi] = *(const bf16x8_t*)&cs[(wm + mi*16 + lrow)*40 + lk8];
      #pragma unroll
      for (int ni = 0; ni < 2; ++ni) bfr[ni] = *(const bf16x8_t*)&cs[(128 + wn + ni*16 + lrow)*40 + lk8];
      #pragma unroll
      for (int mi = 0; mi < 4; ++mi)
        #pragma unroll
        for (int ni = 0; ni < 2; ++ni)
          acc[mi][ni] = __builtin_amdgcn_mfma_f32_16x16x32_bf16(af[mi], bfr[ni], acc[mi][ni], 0, 0, 0);
      if (more){
        st ^= 1;
        *(uint4*)&lds[st][r0*40 + o0] = a0;
        *(uint4*)&lds[st][r1*40 + o0] = a1;
        *(uint4*)&lds[st][(128 + r0)*40 + o0] = b0;
        __syncthreads();
      }
    }
    bf16* Wd = W + (size_t)dir*DMODEL*DINNER;
    #pragma unroll
    for (int mi = 0; mi < 4; ++mi)
      #pragma unroll
      for (int ni = 0; ni < 2; ++ni)
        #pragma unroll
        for (int r = 0; r < 4; ++r){
          int m = m0 + wm + mi*16 + quad*4 + r;
          int n = n0 + wn + ni*16 + lrow;
          Wd[(size_t)m*DINNER + n] = tob(acc[mi][ni][r]);
        }
  } else {
    int sub = bz6 - 64;
    int l0 = (sub & 31)*64, c0 = ((sub >> 5) & 3)*64, b = sub >> 7;
    int tid = t;
    float s = 0.f, ss = 0.f;
    if (tid < 128){ float2 v = pbuf[b*128 + tid]; s = v.x; ss = v.y; }
    for (int o = 32; o > 0; o >>= 1){ s += __shfl_down(s, o, 64); ss += __shfl_down(ss, o, 64); }
    if (tid < 128 && (tid & 63) == 0){ sh[(tid>>6)*2] = s; sh[(tid>>6)*2+1] = ss; }
    __syncthreads();
    float inv = 1.f/(float)(DMODEL*L_SEQ);
    float s0 = sh[0]+sh[2], ss0 = sh[1]+sh[3];
    float mu = s0*inv, var = ss0*inv - mu*mu;
    float istd = rsqrtf(fmaxf(var, 0.f) + 1.1920929e-07f);

    int lx = tid & 63, cy = tid >> 6;
    for (int cc = cy; cc < 64; cc += 4){
      float v = x[(size_t)b*DMODEL*L_SEQ + (size_t)(c0+cc)*L_SEQ + l0+lx];
      tile[cc][lx] = (v - mu)*istd;
    }
    __syncthreads();
    int cx = tid & 63, ly = tid >> 6;
    float w = gw[c0+cx], bb = gb[c0+cx];
    for (int ll = ly; ll < 64; ll += 4)
      t_out[((size_t)(b*L_SEQ) + l0+ll)*DMODEL + c0+cx] = tob(tile[cx][ll]*w + bb);
  }
}

// ---------------- in-proj GEMM 128x128, 512 thr, fused depthwise conv epilogue ---
// grid (608,1,2). K=256. n-tiles 0-7 -> z, 8-17 -> conv+SiLU -> xconv, 18 -> dt.
__global__ __launch_bounds__(512) void gemm_inproj(const bf16* __restrict__ A, const bf16* __restrict__ B,
                                                   bf16* __restrict__ z, bf16* __restrict__ xconv,
                                                   float* __restrict__ dtb,
                                                   const float* __restrict__ db0, const float* __restrict__ db1,
                                                   const float* __restrict__ cw0, const float* __restrict__ cb0,
                                                   const float* __restrict__ cw1, const float* __restrict__ cb1){
  __shared__ __align__(16) bf16 lds[2][(128+128)*40];
  const int lda = DMODEL, ldb = DMODEL, N = DPROJ;
  int dir = blockIdx.z;
  const bf16* Bd = B + (size_t)dir*(size_t)N*ldb;
  int orig = blockIdx.x;
  int swz = (orig & 7)*76 + (orig >> 3);
  int m0 = (swz & 31)*128;
  int n0 = (swz >> 5)*128;
  int t = threadIdx.x;
  int wave = t >> 6, lane = t & 63;
  int wm = (wave & 1)*64, wn = (wave >> 1)*32;
  int lrow = lane & 15, quad = lane >> 4, lk8 = quad*8;

  int rA = t >> 2, oA = (t & 3)*8;
  int amA = m0 + rA;
  if (dir) amA = (amA & ~(L_SEQ-1)) | ((L_SEQ-1) - (amA & (L_SEQ-1)));
  int bnA = n0 + rA; if (bnA > N-1) bnA = N-1;
  const bf16* Ap = A + (size_t)amA*lda + oA;
  const bf16* Bp = Bd + (size_t)bnA*ldb + oA;

  f32x4_t acc[4][2];
  #pragma unroll
  for (int i = 0; i < 4; ++i){ acc[i][0] = (f32x4_t){0,0,0,0}; acc[i][1] = (f32x4_t){0,0,0,0}; }

  int nit = 8;
  uint4 a0 = *(const uint4*)Ap;
  uint4 b0 = *(const uint4*)Bp;
  int st = 0;
  *(uint4*)&lds[0][rA*40 + oA] = a0;
  *(uint4*)&lds[0][(128 + rA)*40 + oA] = b0;
  __syncthreads();
  for (int it = 0; it < nit; ++it){
    bool more = (it+1 < nit);
    if (more){
      int kk = (it+1) << 5;
      a0 = *(const uint4*)(Ap + kk);
      b0 = *(const uint4*)(Bp + kk);
    }
    const bf16* cs = lds[st];
    bf16x8_t bfr[2];
    #pragma unroll
    for (int ni = 0; ni < 2; ++ni) bfr[ni] = *(const bf16x8_t*)&cs[(128 + wn + ni*16 + lrow)*40 + lk8];
    #pragma unroll
    for (int mi = 0; mi < 4; ++mi){
      bf16x8_t af = *(const bf16x8_t*)&cs[(wm + mi*16 + lrow)*40 + lk8];
      #pragma unroll
      for (int ni = 0; ni < 2; ++ni)
        acc[mi][ni] = __builtin_amdgcn_mfma_f32_16x16x32_bf16(af, bfr[ni], acc[mi][ni], 0, 0, 0);
    }
    if (more){
      st ^= 1;
      *(uint4*)&lds[st][rA*40 + oA] = a0;
      *(uint4*)&lds[st][(128 + rA)*40 + oA] = b0;
      __syncthreads();
    }
  }

  if (n0 < DINNER){
    // z region: stage bf16 in LDS, coalesced vector stores
    __syncthreads();
    __bf16* outs = (__bf16*)lds;
    #pragma unroll
    for (int mi = 0; mi < 4; ++mi)
      #pragma unroll
      for (int ni = 0; ni < 2; ++ni)
        #pragma unroll
        for (int r = 0; r < 4; ++r)
          outs[(wm + mi*16 + quad*4 + r)*132 + wn + ni*16 + lrow] = (__bf16)acc[mi][ni][r];
    __syncthreads();
    bf16* dst = z + (size_t)dir*M_TOT*DINNER;
    #pragma unroll
    for (int itv = 0; itv < 4; ++itv){
      int v = t + itv*512;
      int row = v >> 4, cb = v & 15;
      *(bf16x8_t*)&dst[(size_t)(m0+row)*DINNER + n0 + cb*8] =
          *(const bf16x8_t*)&outs[row*132 + cb*8];
    }
  } else if (n0 < DINNER + CONVDIM){
    // xBC region: fused depthwise causal conv + SiLU -> xconv
    bool doHalo = (m0 & (L_SEQ-1)) != 0;
    __syncthreads();
    __bf16* outs = (__bf16*)lds;   // 131 rows x 132: row i = storage m0-3+i
    // halo rows 0..2 (storage m0-3..m0-1): VALU dot recompute, or zeros at batch start
    if (t < 384){
      int hrow = t >> 7, col = t & 127;
      float s = 0.f;
      if (doHalo){
        int mh = m0 - 3 + hrow;
        int amH = mh;
        if (dir) amH = (amH & ~(L_SEQ-1)) | ((L_SEQ-1) - (amH & (L_SEQ-1)));
        const bf16* Arow = A + (size_t)amH*lda;
        const bf16* Brow = Bd + (size_t)(n0 + col)*ldb;
        for (int kk = 0; kk < 32; ++kk){
          bf16x8_t av = *(const bf16x8_t*)&Arow[kk*8];
          bf16x8_t bv = *(const bf16x8_t*)&Brow[kk*8];
          #pragma unroll
          for (int j = 0; j < 8; ++j) s += (float)av[j]*(float)bv[j];
        }
      }
      outs[hrow*132 + col] = (__bf16)s;
    }
    // main rows 3..130 (storage m0..m0+127)
    #pragma unroll
    for (int mi = 0; mi < 4; ++mi)
      #pragma unroll
      for (int ni = 0; ni < 2; ++ni)
        #pragma unroll
        for (int r = 0; r < 4; ++r)
          outs[(3 + wm + mi*16 + quad*4 + r)*132 + wn + ni*16 + lrow] = (__bf16)acc[mi][ni][r];
    __syncthreads();
    int c0 = n0 - DINNER;
    const float* cw  = dir ? cw1 : cw0;
    const float* cbv = dir ? cb1 : cb0;
    bf16* dst = xconv + (size_t)dir*(size_t)M_TOT*CONVDIM;
    #pragma unroll
    for (int itv = 0; itv < 4; ++itv){
      int v = t + itv*512;
      int row = v >> 4, cbk = v & 15;
      int ch0 = c0 + cbk*8;
      bf16x8_t w0 = *(const bf16x8_t*)&outs[(row+0)*132 + cbk*8];
      bf16x8_t w1 = *(const bf16x8_t*)&outs[(row+1)*132 + cbk*8];
      bf16x8_t w2 = *(const bf16x8_t*)&outs[(row+2)*132 + cbk*8];
      bf16x8_t w3 = *(const bf16x8_t*)&outs[(row+3)*132 + cbk*8];
      bf16x8_t ov;
      #pragma unroll
      for (int j = 0; j < 8; ++j){
        float4 wj = *(const float4*)&cw[(ch0+j)*4];
        float a = cbv[ch0+j] + (float)w0[j]*wj.x + (float)w1[j]*wj.y
                             + (float)w2[j]*wj.z + (float)w3[j]*wj.w;
        ov[j] = (__bf16)(a / (1.f + __expf(-a)));
      }
      *(bf16x8_t*)&dst[(size_t)(m0+row)*CONVDIM + ch0] = ov;
    }
  } else {
    // dt tile: scalar fp32 softplus path (unchanged numerics)
    const float* db = dir ? db1 : db0;
    float* dtp = dtb + (size_t)dir*((size_t)M_TOT*NH);
    #pragma unroll
    for (int mi = 0; mi < 4; ++mi)
      #pragma unroll
      for (int ni = 0; ni < 2; ++ni)
        #pragma unroll
        for (int r = 0; r < 4; ++r){
          int m = m0 + wm + mi*16 + quad*4 + r;
          int n = n0 + wn + ni*16 + lrow;
          if (n < N){
            int h = n - (DINNER + CONVDIM);
            float xx = acc[mi][ni][r] + db[h];
            dtp[(size_t)m*NH + h] = (xx > 20.f) ? xx : log1pf(expf(xx));
          }
        }
  }
}

// ---------------- fused final GEMM + epilogue, BK=64, prefetch-2 -----------------
__global__ __launch_bounds__(256) void gemm_final(const bf16* __restrict__ y, const bf16* __restrict__ tb,
                                                  const bf16* __restrict__ W, const bf16* __restrict__ psum,
                                                  const float* __restrict__ x, const float* __restrict__ pb,
                                                  float* __restrict__ out){
  __shared__ __align__(16) bf16 lds[2][(32+64)*72];
  __shared__ float tile[32][65];
  int orig = blockIdx.x;
  int swz = (orig & 7)*64 + (orig >> 3);   // 512 = 8*64, bijective
  int mt_ = swz & 127, nt_ = swz >> 7;
  int m0 = mt_*32, n0 = nt_*64;
  int t = threadIdx.x;
  int wave = t >> 6, lane = t & 63;
  int lrow = lane & 15, quad = lane >> 4, lk8 = quad*8;
  int wn = wave*16;

  f32x4_t acc[2];
  acc[0] = (f32x4_t){0,0,0,0}; acc[1] = (f32x4_t){0,0,0,0};

  int rowA = t >> 3, oA = (t & 7)*8;
  int rowB0 = t >> 3, oB0 = (t & 7)*8;
  int rowB1 = (t + 256) >> 3, oB1 = (t & 7)*8;

  #pragma unroll
  for (int ph = 0; ph < 3; ++ph){
    const bf16 *Ab, *Bb; int lda, ldb, K, rev;
    if (ph == 0){ Ab = y;                             lda = DINNER; K = DINNER; Bb = W;                             ldb = DINNER; rev = 0; }
    else if (ph == 1){ Ab = y + (size_t)M_TOT*DINNER; lda = DINNER; K = DINNER; Bb = W + (size_t)DMODEL*DINNER;     ldb = DINNER; rev = 1; }
    else { Ab = tb; lda = DMODEL; K = DMODEL; Bb = psum; ldb = DMODEL; rev = 0; }

    int am = m0 + rowA;
    if (rev) am = (am & ~(L_SEQ-1)) | ((L_SEQ-1) - (am & (L_SEQ-1)));
    const bf16* Ap  = Ab + (size_t)am*lda + oA;
    const bf16* Bp0 = Bb + (size_t)(n0 + rowB0)*ldb + oB0;
    const bf16* Bp1 = Bb + (size_t)(n0 + rowB1)*ldb + oB1;

    int nit = K >> 6;
    uint4 au  = *(const uint4*)Ap;
    uint4 bu0 = *(const uint4*)Bp0;
    uint4 bu1 = *(const uint4*)Bp1;
    uint4 av  = *(const uint4*)(Ap + 64);
    uint4 bv0 = *(const uint4*)(Bp0 + 64);
    uint4 bv1 = *(const uint4*)(Bp1 + 64);

#define FSTAGE(buf, A_, B0_, B1_) \
    *(uint4*)&lds[buf][rowA*72 + oA] = A_; \
    *(uint4*)&lds[buf][(32 + rowB0)*72 + oB0] = B0_; \
    *(uint4*)&lds[buf][(32 + rowB1)*72 + oB1] = B1_;

#define FCOMP(buf) { \
    const bf16* cs = lds[buf]; \
    _Pragma("unroll") \
    for (int ks = 0; ks < 2; ++ks){ \
      bf16x8_t bq = *(const bf16x8_t*)&cs[(32 + wn + lrow)*72 + ks*32 + lk8]; \
      _Pragma("unroll") \
      for (int mt = 0; mt < 2; ++mt){ \
        bf16x8_t af = *(const bf16x8_t*)&cs[(mt*16 + lrow)*72 + ks*32 + lk8]; \
        acc[mt] = __builtin_amdgcn_mfma_f32_16x16x32_bf16(af, bq, acc[mt], 0, 0, 0); \
      } \
    } }

    __syncthreads();
    FSTAGE(0, au, bu0, bu1)
    __syncthreads();
    for (int it = 0; it < nit; it += 2){
      if (it + 2 < nit){
        int kk = (it+2) << 6;
        au = *(const uint4*)(Ap+kk); bu0 = *(const uint4*)(Bp0+kk); bu1 = *(const uint4*)(Bp1+kk);
      }
      FCOMP(0)
      FSTAGE(1, av, bv0, bv1)
      __syncthreads();
      if (it + 3 < nit){
        int kk = (it+3) << 6;
        av = *(const uint4*)(Ap+kk); bv0 = *(const uint4*)(Bp0+kk); bv1 = *(const uint4*)(Bp1+kk);
      }
      FCOMP(1)
      if (it + 2 < nit){
        FSTAGE(0, au, bu0, bu1)
        __syncthreads();
      }
    }
#undef FSTAGE
#undef FCOMP
  }

  #pragma unroll
  for (int mt = 0; mt < 2; ++mt)
    #pragma unroll
    for (int r = 0; r < 4; ++r)
      tile[mt*16 + quad*4 + r][wn + lrow] = acc[mt][r];
  __syncthreads();
  int b = m0 >> 11, l0 = m0 & (L_SEQ-1);
  int tx = t & 31, ny = t >> 5;
  for (int nn = ny; nn < 64; nn += 8){
    int n = n0 + nn;
    size_t xi = (size_t)b*DMODEL*L_SEQ + (size_t)n*L_SEQ + l0 + tx;
    out[xi] = tile[tx][nn] + pb[n] + x[xi];
  }
}

// ---------------- merged: per-chunk states+scan (0-511) | CB GEMM (512-1023) -----
__global__ __launch_bounds__(256) void k_states_cb(const bf16* __restrict__ xconv, const float* __restrict__ dt,
                                                   const float* __restrict__ Al0, const float* __restrict__ Al1,
                                                   float* __restrict__ A_cs, float* __restrict__ states,
                                                   bf16* __restrict__ CB){
  __shared__ __align__(16) char smem[34816];
  int bz = blockIdx.x, t = threadIdx.x;
  if (bz < 512){
    float* s_acs = (float*)smem;
    float* w_s   = (float*)(smem + 1024);
    __bf16* Xt   = (__bf16*)(smem + 2048);
    __bf16* Bt   = (__bf16*)(smem + 2048 + 9216);
    int id0 = bz;
    int dir = id0 >> 8; int id = id0 & 255;
    int h = id & 15; int bc = id >> 4; int ch = bc & 7; int b = bc >> 3;
    const bf16* xc = xconv + (size_t)dir*((size_t)M_TOT*CONVDIM);
    const float* dtp = dt + (size_t)dir*((size_t)M_TOT*NH);
    const float* Alog = dir ? Al1 : Al0;
    size_t rowbase = (size_t)(b*L_SEQ) + ch*CT;

    float dtv = dtp[(rowbase + t)*NH + h];
    s_acs[t] = -expf(Alog[h]) * dtv;
    __syncthreads();
    for (int off = 1; off < 256; off <<= 1){
      float v = (t >= off) ? s_acs[t-off] : 0.f;
      __syncthreads();
      s_acs[t] += v;
      __syncthreads();
    }
    A_cs[(size_t)dir*ACS_N + (size_t)((b*NH+h)*NCHK + ch)*CT + t] = s_acs[t];
    float alast = s_acs[CT-1];
    w_s[t] = dtv * __expf(fminf(alast - s_acs[t], 0.f));
    __syncthreads();

    int wave = t >> 6, lane = t & 63, lrow = lane & 15, quad = lane >> 4;
    f32x4_t acc[8];
    #pragma unroll
    for (int i = 0; i < 8; ++i) acc[i] = (f32x4_t){0.f,0.f,0.f,0.f};

    for (int kt = 0; kt < 4; ++kt){
      int l0 = kt*64;
      #pragma unroll
      for (int it = 0; it < 2; ++it){
        int idx = t + it*256; int l = idx >> 3; int p0 = (idx & 7)*8;
        bf16x8_t v = *(const bf16x8_t*)&xc[(rowbase + l0 + l)*CONVDIM + h*HD + p0];
        float w = w_s[l0 + l];
        int col = (((l>>3) ^ ((p0>>3)&7))<<3) | (l&7);
        #pragma unroll
        for (int j = 0; j < 8; ++j) Xt[(p0+j)*72 + col] = (__bf16)((float)v[j]*w);
      }
      #pragma unroll
      for (int it = 0; it < 4; ++it){
        int idx = t + it*256; int l = idx >> 4; int n0 = (idx & 15)*8;
        bf16x8_t v = *(const bf16x8_t*)&xc[(rowbase + l0 + l)*CONVDIM + DINNER + n0];
        int col = (((l>>3) ^ ((n0>>3)&7))<<3) | (l&7);
        #pragma unroll
        for (int j = 0; j < 8; ++j) Bt[(n0+j)*72 + col] = v[j];
      }
      __syncthreads();
      int arow = wave*16 + lrow;
      #pragma unroll
      for (int ks = 0; ks < 2; ++ks){
        int kg = ks*4 + quad;
        bf16x8_t af = *(const bf16x8_t*)&Xt[arow*72 + ((kg ^ ((arow>>3)&7))<<3)];
        #pragma unroll
        for (int nt = 0; nt < 8; ++nt){
          int brow = nt*16 + lrow;
          bf16x8_t bq = *(const bf16x8_t*)&Bt[brow*72 + ((kg ^ ((brow>>3)&7))<<3)];
          acc[nt] = __builtin_amdgcn_mfma_f32_16x16x32_bf16(af, bq, acc[nt], 0, 0, 0);
        }
      }
      __syncthreads();
    }
    float* so = states + (size_t)dir*ST_N + (size_t)id*HD*DSTATE;
    int m = wave*16 + quad*4;
    #pragma unroll
    for (int nt = 0; nt < 8; ++nt)
      #pragma unroll
      for (int r = 0; r < 4; ++r)
        so[(size_t)(m+r)*DSTATE + nt*16 + lrow] = acc[nt][r];
  } else {
    __bf16* As = (__bf16*)smem;
    __bf16* Bs = (__bf16*)(smem + 17408);
    int sub = bz - 512;
    int zz = sub >> 4;
    int dir = zz >> 4; int b = (zz >> 3) & 1; int ch = zz & 7;
    int rest = sub & 15;
    int m0 = (rest >> 2)*64, n0 = (rest & 3)*64;
    if (n0 > m0) return;
    const bf16* base = xconv + (size_t)dir*((size_t)M_TOT*CONVDIM) + (size_t)(b*L_SEQ + ch*CT)*CONVDIM;
    const bf16* Crow = base + DINNER + DSTATE;
    const bf16* Brow = base + DINNER;
    int r = t >> 2, o0 = (t & 3)*32;
    #pragma unroll
    for (int j = 0; j < 4; ++j){
      *(bf16x8_t*)&As[r*136 + o0 + j*8] = *(const bf16x8_t*)&Crow[(size_t)(m0+r)*CONVDIM + o0 + j*8];
      *(bf16x8_t*)&Bs[r*136 + o0 + j*8] = *(const bf16x8_t*)&Brow[(size_t)(n0+r)*CONVDIM + o0 + j*8];
    }
    __syncthreads();
    int wave = t >> 6, lane = t & 63, lrow = lane & 15, quad = lane >> 4;
    int wm = wave*16;
    f32x4_t acc[4];
    #pragma unroll
    for (int i = 0; i < 4; ++i) acc[i] = (f32x4_t){0.f,0.f,0.f,0.f};
    #pragma unroll
    for (int ks = 0; ks < 4; ++ks){
      bf16x8_t af = *(const bf16x8_t*)&As[(wm+lrow)*136 + ks*32 + quad*8];
      #pragma unroll
      for (int nt = 0; nt < 4; ++nt){
        bf16x8_t bq = *(const bf16x8_t*)&Bs[(nt*16+lrow)*136 + ks*32 + quad*8];
        acc[nt] = __builtin_amdgcn_mfma_f32_16x16x32_bf16(af, bq, acc[nt], 0, 0, 0);
      }
    }
    __syncthreads();
    #pragma unroll
    for (int nt = 0; nt < 4; ++nt)
      #pragma unroll
      for (int r2 = 0; r2 < 4; ++r2)
        As[(wm + quad*4 + r2)*72 + nt*16 + lrow] = (__bf16)acc[nt][r2];
    __syncthreads();
    bf16* outp = CB + (size_t)dir*CB_N + (size_t)(b*NCHK+ch)*CT*CT;
    #pragma unroll
    for (int p = 0; p < 2; ++p){
      int idx = t + p*256;
      int row = idx >> 3, c8 = (idx & 7)*8;
      *(bf16x8_t*)&outp[(size_t)(m0+row)*CT + n0 + c8] = *(const bf16x8_t*)&As[row*72 + c8];
    }
  }
}

// ---------------- inter-chunk recurrence: emits bf16 prefix states ---------------
__global__ __launch_bounds__(256) void k_recur(const float* __restrict__ states, bf16* __restrict__ nsb,
                                               const float* __restrict__ A_cs){
  int blk = blockIdx.x;
  int bh2 = blk >> 5;
  int e = (blk & 31)*256 + threadIdx.x;
  int dir = bh2 >> 5; int bh = bh2 & 31;
  int h = bh & 15, b = bh >> 4;
  const float* ac = A_cs + (size_t)dir*ACS_N;
  const float* st = states + (size_t)dir*ST_N;
  bf16* nb = nsb + (size_t)dir*ST_N;
  float s = 0.f;
  #pragma unroll
  for (int ch = 0; ch < NCHK; ++ch){
    float dec = expdec(ac[((size_t)(bh*NCHK+ch))*CT + CT-1]);
    size_t off = (size_t)(((b*NCHK+ch)*NH)+h)*HD*DSTATE + e;
    float cur = st[off];
    nb[off] = tob(s);
    s = s*dec + cur;
  }
}

// ---------------- Y = (L*CB)@X + exp(Acs)*(C@NS)  MFMA, triangle-balanced waves --
__global__ __launch_bounds__(512) void k_y_mfma(const bf16* __restrict__ xconv, const float* __restrict__ dt,
                                                const float* __restrict__ A_cs, const bf16* __restrict__ CB,
                                                const bf16* __restrict__ ns, bf16* __restrict__ y){
  int id0 = blockIdx.x;
  int dir = id0 >> 8; int id = id0 & 255;
  int h = id & 15; int bc = id >> 4; int ch = bc & 7; int b = bc >> 3;
  int t = threadIdx.x;
  int lane = t & 63;
  int lrow = lane & 15, quad = lane >> 4;

  __shared__ __align__(16) bf16 Xs[64*264];
  __shared__ __align__(16) bf16 NSs[64*136];
  __shared__ float acs_s[CT];

  const bf16* xc = xconv + (size_t)dir*((size_t)M_TOT*CONVDIM);
  const float* dtp = dt + (size_t)dir*((size_t)M_TOT*NH);
  const float* acs = A_cs + (size_t)dir*ACS_N + (size_t)((b*NH+h)*NCHK + ch)*CT;
  const bf16* cbz = CB + (size_t)dir*CB_N + (size_t)(b*NCHK+ch)*CT*CT;
  const bf16* nsp = ns + (size_t)dir*ST_N + (size_t)(((b*NCHK+ch)*NH)+h)*HD*DSTATE;
  bf16* yp = y + (size_t)dir*((size_t)M_TOT*DINNER);
  size_t rowbase = (size_t)(b*L_SEQ + ch*CT);
  if (t < CT) acs_s[t] = acs[t];

  #pragma unroll
  for (int it = 0; it < 4; ++it){
    int idx = t + it*512;
    int s = idx >> 3, p0 = (idx & 7)*8;
    float dtv = dtp[(rowbase + s)*NH + h];
    bf16x8_t v = *(const bf16x8_t*)&xc[(rowbase + s)*CONVDIM + h*HD + p0];
    int col = ((((s>>3) ^ ((p0>>3)&7)))<<3) | (s&7);
    #pragma unroll
    for (int j = 0; j < 8; ++j)
      Xs[(p0+j)*264 + col] = tob((float)v[j] * dtv);
  }
  #pragma unroll
  for (int it = 0; it < 2; ++it){
    int idx = t + it*512;
    int p = idx >> 4, n8 = (idx & 15)*8;
    *(bf16x8_t*)&NSs[p*136 + n8] = *(const bf16x8_t*)&nsp[(size_t)p*DSTATE + n8];
  }
  __syncthreads();

  int wave = t >> 6;                  // [0,8)
  int sA = wave, sB = 15 - wave;      // paired strips, uniform total work
  float alA = acs_s[sA*16 + lrow];
  float alB = acs_s[sB*16 + lrow];

  f32x4_t acc[2][4];
  #pragma unroll
  for (int i = 0; i < 2; ++i)
    #pragma unroll
    for (int j = 0; j < 4; ++j) acc[i][j] = (f32x4_t){0.f,0.f,0.f,0.f};

  #pragma unroll
  for (int sp = 0; sp < 2; ++sp){
    int s = sp ? sB : sA;
    float al = sp ? alB : alA;
    int r0s = s*16;
    float a0r = acs_s[r0s];
    int nst = (s >> 1) + 1;
    for (int st = 0; st < nst; ++st){
      int s0 = st*32;
      if (s0 + 31 < r0s && (a0r - acs_s[s0+31]) < -30.f) continue;
      int sg = (s0 >> 3) + quad;
      bf16x8_t bq[4];
      #pragma unroll
      for (int nt = 0; nt < 4; ++nt){
        int brow = nt*16 + lrow;
        bq[nt] = *(const bf16x8_t*)&Xs[brow*264 + ((sg ^ ((brow>>3)&7))<<3)];
      }
      int l = r0s + lrow;
      bf16x8_t cvv = *(const bf16x8_t*)&cbz[(size_t)l*CT + s0 + quad*8];
      union { bf16x8_t v; __bf16 e[8]; } wa;
      #pragma unroll
      for (int j = 0; j < 8; ++j){
        int sI = s0 + quad*8 + j;
        float w = (sI <= l) ? __expf(fminf(al - acs_s[sI], 0.f)) * (float)cvv[j] : 0.f;
        wa.e[j] = (__bf16)w;
      }
      #pragma unroll
      for (int nt = 0; nt < 4; ++nt)
        acc[sp][nt] = __builtin_amdgcn_mfma_f32_16x16x32_bf16(wa.v, bq[nt], acc[sp][nt], 0, 0, 0);
    }
  }

  float elA = expdec(alA);
  float elB = expdec(alB);
  #pragma unroll
  for (int kt = 0; kt < 4; ++kt){
    int n0 = kt*32;
    bf16x8_t bq[4];
    #pragma unroll
    for (int nt = 0; nt < 4; ++nt)
      bq[nt] = *(const bf16x8_t*)&NSs[(nt*16+lrow)*136 + n0 + quad*8];
    #pragma unroll
    for (int sp = 0; sp < 2; ++sp){
      int s = sp ? sB : sA;
      float el = sp ? elB : elA;
      int l = s*16 + lrow;
      union { bf16x8_t v; __bf16 e[8]; } cu;
      cu.v = *(const bf16x8_t*)&xc[(rowbase + l)*CONVDIM + DINNER + DSTATE + n0 + quad*8];
      union { bf16x8_t v; __bf16 e[8]; } wa;
      #pragma unroll
      for (int j = 0; j < 8; ++j) wa.e[j] = (__bf16)((float)cu.e[j] * el);
      #pragma unroll
      for (int nt = 0; nt < 4; ++nt)
        acc[sp][nt] = __builtin_amdgcn_mfma_f32_16x16x32_bf16(wa.v, bq[nt], acc[sp][nt], 0, 0, 0);
    }
  }

  #pragma unroll
  for (int sp = 0; sp < 2; ++sp){
    int s = sp ? sB : sA;
    #pragma unroll
    for (int nt = 0; nt < 4; ++nt)
      #pragma unroll
      for (int rr = 0; rr < 4; ++rr){
        int l = s*16 + quad*4 + rr;
        int p = nt*16 + lrow;
        yp[(rowbase + l)*DINNER + h*HD + p] = tob(acc[sp][nt][rr]);
      }
  }
}

// ---------------- gate ((y + D*x) * silu(z)) + RMSNorm, vectorized ---------------
__global__ __launch_bounds__(256) void k_gaterms(const bf16* __restrict__ z, const float* __restrict__ nw0,
                                                 const float* __restrict__ nw1, const bf16* __restrict__ xconv,
                                                 const float* __restrict__ Dh0, const float* __restrict__ Dh1,
                                                 bf16* __restrict__ y){
  int m0 = blockIdx.x;
  int dir = m0 >> 12; int m = m0 & (M_TOT-1);
  int t = threadIdx.x;
  const float* nw = dir ? nw1 : nw0;
  const float* Dh = dir ? Dh1 : Dh0;
  int j0 = t*4;
  const bf16* zp = z + (size_t)dir*((size_t)M_TOT*DINNER) + (size_t)m*DINNER;
  const bf16* xc = xconv + (size_t)dir*((size_t)M_TOT*CONVDIM) + (size_t)m*CONVDIM;
  bf16* yp = y + (size_t)dir*((size_t)M_TOT*DINNER) + (size_t)m*DINNER;

  bf16x4_t zv = *(const bf16x4_t*)&zp[j0];
  bf16x4_t yv = *(const bf16x4_t*)&yp[j0];
  bf16x4_t xv = *(const bf16x4_t*)&xc[j0];
  float Dv = Dh[j0 >> 6];
  float v[4]; float ss = 0.f;
  #pragma unroll
  for (int c = 0; c < 4; ++c){
    float zf = (float)zv[c];
    float raw = (float)yv[c] + Dv*(float)xv[c];
    float g = raw * (zf / (1.f + __expf(-zf)));
    v[c] = g; ss += g*g;
  }
  for (int o = 32; o > 0; o >>= 1) ss += __shfl_down(ss, o, 64);
  __shared__ float sh[4];
  if ((t & 63) == 0) sh[t>>6] = ss;
  __syncthreads();
  ss = sh[0]+sh[1]+sh[2]+sh[3];
  float scale = rsqrtf(ss*(1.f/DINNER) + 1e-5f);
  float4 nwv = *(const float4*)&nw[j0];
  float nws[4] = {nwv.x, nwv.y, nwv.z, nwv.w};
  bf16x4_t o;
  #pragma unroll
  for (int c = 0; c < 4; ++c) o[c] = (__bf16)(v[c]*scale*nws[c]);
  *(bf16x4_t*)&yp[j0] = o;
}

extern "C" void kernel_launch(void* const* d_in, const int* in_sizes, int n_in,
                              void* d_out, int out_size, void* d_ws, size_t ws_size,
                              hipStream_t stream){
  (void)in_sizes; (void)n_in; (void)out_size; (void)ws_size;
  const float* x      = (const float*)d_in[0];
  const float* gn_w   = (const float*)d_in[1];
  const float* gn_b   = (const float*)d_in[2];
  const float* proj_w = (const float*)d_in[3];
  const float* proj_b = (const float*)d_in[4];
  float* out = (float*)d_out;

  char* wp = (char*)d_ws;
  auto alloc = [&](size_t bytes){ void* r = (void*)wp; wp += (bytes + 255) & ~(size_t)255; return r; };
  bf16*  t_buf  = (bf16*) alloc((size_t)M_TOT*DMODEL*2);
  bf16*  z_buf  = (bf16*) alloc((size_t)2*M_TOT*DINNER*2);
  bf16*  xraw   = (bf16*) alloc((size_t)2*M_TOT*CONVDIM*2);   // used only as y_buf now
  bf16*  xconv  = (bf16*) alloc((size_t)2*M_TOT*CONVDIM*2);
  float* dt_buf = (float*)alloc((size_t)2*M_TOT*NH*4);
  float* acs    = (float*)alloc((size_t)2*ACS_N*4);
  float* states = (float*)alloc((size_t)2*ST_N*4);
  bf16*  nsb    = (bf16*) alloc((size_t)2*ST_N*2);
  bf16*  cb     = (bf16*) alloc((size_t)2*CB_N*2);
  float2* pbuf  = (float2*)alloc(BATCH*128*sizeof(float2));
  bf16*  inw_bf   = (bf16*)alloc((size_t)2*DPROJ*DMODEL*2);
  bf16*  projw_bf = (bf16*)alloc((size_t)DMODEL*2*DMODEL*2);
  bf16*  owt      = (bf16*)alloc((size_t)2*DINNER*DMODEL*2);
  bf16*  wfb      = (bf16*)alloc((size_t)2*DMODEL*DINNER*2);
  bf16*  psum     = (bf16*)alloc((size_t)DMODEL*DMODEL*2);
  bf16*  y_buf    = xraw;

  k_front<<<1704, 256, 0, stream>>>(
      (const float*)d_in[5], (const float*)d_in[13], proj_w,
      inw_bf, projw_bf,
      (const float*)d_in[12], (const float*)d_in[20], owt, psum,
      x, pbuf);

  k_wt<<<320, 256, 0, stream>>>(projw_bf, owt, wfb, x, gn_w, gn_b, pbuf, t_buf);

  gemm_inproj<<<dim3(608, 1, 2), 512, 0, stream>>>(
      t_buf, inw_bf, z_buf, xconv, dt_buf,
      (const float*)d_in[8], (const float*)d_in[16],
      (const float*)d_in[6], (const float*)d_in[7],
      (const float*)d_in[14], (const float*)d_in[15]);

  k_states_cb<<<1024, 256, 0, stream>>>(
      xconv, dt_buf, (const float*)d_in[9], (const float*)d_in[17], acs, states, cb);
  k_recur<<<2*BATCH*NH*32, 256, 0, stream>>>(states, nsb, acs);
  k_y_mfma<<<2*BATCH*NCHK*NH, 512, 0, stream>>>(xconv, dt_buf, acs, cb, nsb, y_buf);
  k_gaterms<<<2*M_TOT, 256, 0, stream>>>(
      z_buf, (const float*)d_in[11], (const float*)d_in[19], xconv,
      (const float*)d_in[10], (const float*)d_in[18], y_buf);

  gemm_final<<<512, 256, 0, stream>>>(y_buf, t_buf, wfb, psum, x, proj_b, out);
}

// Round 15
// 207.102 us; speedup vs baseline: 1.3613x; 1.3613x over previous
//
#include <hip/hip_runtime.h>
#include <hip/hip_bf16.h>
#include <math.h>

using bf16 = __hip_bfloat16;

#define L_SEQ   2048
#define DMODEL  256
#define DINNER  1024
#define DSTATE  128
#define NH      16
#define HD      64
#define CONVDIM 1280
#define DPROJ   2320
#define NCHK    8
#define CT      256
#define BATCH   2
#define M_TOT   (BATCH*L_SEQ)

#define ACS_N   (BATCH*NH*NCHK*CT)
#define ST_N    ((size_t)BATCH*NCHK*NH*HD*DSTATE)
#define CB_N    ((size_t)BATCH*NCHK*CT*CT)

typedef __bf16 bf16x8_t __attribute__((ext_vector_type(8)));
typedef __bf16 bf16x4_t __attribute__((ext_vector_type(4)));
typedef float  f32x4_t  __attribute__((ext_vector_type(4)));

__device__ __forceinline__ float tof(bf16 v){ return __bfloat162float(v); }
__device__ __forceinline__ bf16  tob(float v){ return __float2bfloat16(v); }
__device__ __forceinline__ float expdec(float a){ return __expf(fminf(a, 0.f)); }

// ---------------- front mega-kernel: weight casts + owt/psum prep + batch stats --
__global__ __launch_bounds__(256) void k_front(
    const float* __restrict__ iw0, const float* __restrict__ iw1, const float* __restrict__ pw,
    bf16* __restrict__ inw_bf, bf16* __restrict__ projw_bf,
    const float* __restrict__ ow0, const float* __restrict__ ow1,
    bf16* __restrict__ owt, bf16* __restrict__ psum,
    const float* __restrict__ x, float2* __restrict__ pbuf){
  __shared__ __bf16 tile[64][65];
  __shared__ float sh[8];
  int bz = blockIdx.x, t = threadIdx.x;
  if (bz < 1160){
    int dir = bz >= 580; int sub = dir ? bz - 580 : bz;
    const float* src = dir ? iw1 : iw0;
    bf16* dst = inw_bf + (size_t)dir*DPROJ*DMODEL;
    int i = (sub*256 + t)*4;
    float4 v = *(const float4*)(src + i);
    dst[i]   = tob(v.x); dst[i+1] = tob(v.y);
    dst[i+2] = tob(v.z); dst[i+3] = tob(v.w);
  } else if (bz < 1288){
    int i = ((bz-1160)*256 + t)*4;
    float4 v = *(const float4*)(pw + i);
    projw_bf[i]   = tob(v.x); projw_bf[i+1] = tob(v.y);
    projw_bf[i+2] = tob(v.z); projw_bf[i+3] = tob(v.w);
  } else if (bz < 1416){
    int sub = bz - 1288;
    int dir = sub >> 6; int tid = sub & 63;
    int k0 = (tid >> 2)*64, j0 = (tid & 3)*64;
    const float* src = dir ? ow1 : ow0;
    bf16* dst = owt + (size_t)dir*DINNER*DMODEL;
    #pragma unroll
    for (int it = 0; it < 2; ++it){
      int idx = t + it*256; int jj = idx >> 3; int k8 = (idx & 7)*8;
      float4 va = *(const float4*)&src[(size_t)(j0+jj)*DINNER + k0 + k8];
      float4 vb = *(const float4*)&src[(size_t)(j0+jj)*DINNER + k0 + k8 + 4];
      tile[k8+0][jj] = (__bf16)va.x; tile[k8+1][jj] = (__bf16)va.y;
      tile[k8+2][jj] = (__bf16)va.z; tile[k8+3][jj] = (__bf16)va.w;
      tile[k8+4][jj] = (__bf16)vb.x; tile[k8+5][jj] = (__bf16)vb.y;
      tile[k8+6][jj] = (__bf16)vb.z; tile[k8+7][jj] = (__bf16)vb.w;
    }
    __syncthreads();
    #pragma unroll
    for (int it = 0; it < 2; ++it){
      int idx = t + it*256; int kr = idx >> 3; int j8 = (idx & 7)*8;
      bf16x8_t o;
      #pragma unroll
      for (int i = 0; i < 8; ++i) o[i] = tile[kr][j8+i];
      *(bf16x8_t*)&dst[(size_t)(k0+kr)*DMODEL + j0 + j8] = o;
    }
  } else if (bz < 1448){
    int i = ((bz - 1416)*256 + t)*8;
    int j = i & 255;
    const float* row = pw + (size_t)(i >> 8)*(2*DMODEL);
    bf16x8_t o;
    #pragma unroll
    for (int c = 0; c < 8; ++c) o[c] = (__bf16)(row[j+c] + row[256+j+c]);
    *(bf16x8_t*)&psum[i] = o;
  } else {
    int sub = bz - 1448;
    int blk = sub & 127, b = sub >> 7;
    const float4* p = (const float4*)(x + (size_t)b*(DMODEL*L_SEQ) + (size_t)blk*4096);
    float s = 0.f, ss = 0.f;
    #pragma unroll
    for (int k = 0; k < 4; ++k){
      float4 v = p[t + k*256];
      s  += v.x + v.y + v.z + v.w;
      ss += v.x*v.x + v.y*v.y + v.z*v.z + v.w*v.w;
    }
    for (int o = 32; o > 0; o >>= 1){ s += __shfl_down(s, o, 64); ss += __shfl_down(ss, o, 64); }
    if ((t & 63) == 0){ sh[(t>>6)*2] = s; sh[(t>>6)*2+1] = ss; }
    __syncthreads();
    if (t == 0){
      s  = sh[0]+sh[2]+sh[4]+sh[6];
      ss = sh[1]+sh[3]+sh[5]+sh[7];
      pbuf[b*128 + blk] = make_float2(s, ss);
    }
  }
}

// ---------------- merged: W = P@owt (blocks 0-63) + GroupNorm/transpose (64-319) -
__global__ __launch_bounds__(256) void k_wt(const bf16* __restrict__ P, const bf16* __restrict__ owt,
                                            bf16* __restrict__ W,
                                            const float* __restrict__ x, const float* __restrict__ gw,
                                            const float* __restrict__ gb, const float2* __restrict__ pbuf,
                                            bf16* __restrict__ t_out){
  __shared__ __align__(16) bf16 lds[2][(128+64)*40];
  __shared__ float tile[64][65];
  __shared__ float sh[4];
  int bz6 = blockIdx.x;
  int t = threadIdx.x;
  if (bz6 < 64){
    int dir = bz6 & 1;
    int m0 = (bz6 >> 5)*128, n0 = ((bz6 >> 1) & 15)*64;
    int wave = t >> 6, lane = t & 63;
    int wm = (wave & 1)*64, wn = (wave >> 1)*32;
    int lrow = lane & 15, quad = lane >> 4, lk8 = quad*8;

    int r0 = t >> 2, o0 = (t & 3)*8;
    int r1 = r0 + 64;
    const bf16* Ap0 = P + (size_t)(m0 + r0)*(2*DMODEL) + dir*DMODEL + o0;
    const bf16* Ap1 = P + (size_t)(m0 + r1)*(2*DMODEL) + dir*DMODEL + o0;
    const bf16* Bp  = owt + (size_t)dir*DINNER*DMODEL + (size_t)(n0 + r0)*DMODEL + o0;

    f32x4_t acc[4][2];
    #pragma unroll
    for (int i = 0; i < 4; ++i){ acc[i][0] = (f32x4_t){0,0,0,0}; acc[i][1] = (f32x4_t){0,0,0,0}; }

    int nit = DMODEL >> 5;  // 8
    uint4 a0 = *(const uint4*)Ap0;
    uint4 a1 = *(const uint4*)Ap1;
    uint4 b0 = *(const uint4*)Bp;
    int st = 0;
    *(uint4*)&lds[0][r0*40 + o0] = a0;
    *(uint4*)&lds[0][r1*40 + o0] = a1;
    *(uint4*)&lds[0][(128 + r0)*40 + o0] = b0;
    __syncthreads();
    for (int it = 0; it < nit; ++it){
      bool more = (it+1 < nit);
      if (more){
        int kk = (it+1) << 5;
        a0 = *(const uint4*)(Ap0 + kk);
        a1 = *(const uint4*)(Ap1 + kk);
        b0 = *(const uint4*)(Bp + kk);
      }
      const bf16* cs = lds[st];
      bf16x8_t af[4], bfr[2];
      #pragma unroll
      for (int mi = 0; mi < 4; ++mi) af[mi] = *(const bf16x8_t*)&cs[(wm + mi*16 + lrow)*40 + lk8];
      #pragma unroll
      for (int ni = 0; ni < 2; ++ni) bfr[ni] = *(const bf16x8_t*)&cs[(128 + wn + ni*16 + lrow)*40 + lk8];
      #pragma unroll
      for (int mi = 0; mi < 4; ++mi)
        #pragma unroll
        for (int ni = 0; ni < 2; ++ni)
          acc[mi][ni] = __builtin_amdgcn_mfma_f32_16x16x32_bf16(af[mi], bfr[ni], acc[mi][ni], 0, 0, 0);
      if (more){
        st ^= 1;
        *(uint4*)&lds[st][r0*40 + o0] = a0;
        *(uint4*)&lds[st][r1*40 + o0] = a1;
        *(uint4*)&lds[st][(128 + r0)*40 + o0] = b0;
        __syncthreads();
      }
    }
    bf16* Wd = W + (size_t)dir*DMODEL*DINNER;
    #pragma unroll
    for (int mi = 0; mi < 4; ++mi)
      #pragma unroll
      for (int ni = 0; ni < 2; ++ni)
        #pragma unroll
        for (int r = 0; r < 4; ++r){
          int m = m0 + wm + mi*16 + quad*4 + r;
          int n = n0 + wn + ni*16 + lrow;
          Wd[(size_t)m*DINNER + n] = tob(acc[mi][ni][r]);
        }
  } else {
    int sub = bz6 - 64;
    int l0 = (sub & 31)*64, c0 = ((sub >> 5) & 3)*64, b = sub >> 7;
    int tid = t;
    float s = 0.f, ss = 0.f;
    if (tid < 128){ float2 v = pbuf[b*128 + tid]; s = v.x; ss = v.y; }
    for (int o = 32; o > 0; o >>= 1){ s += __shfl_down(s, o, 64); ss += __shfl_down(ss, o, 64); }
    if (tid < 128 && (tid & 63) == 0){ sh[(tid>>6)*2] = s; sh[(tid>>6)*2+1] = ss; }
    __syncthreads();
    float inv = 1.f/(float)(DMODEL*L_SEQ);
    float s0 = sh[0]+sh[2], ss0 = sh[1]+sh[3];
    float mu = s0*inv, var = ss0*inv - mu*mu;
    float istd = rsqrtf(fmaxf(var, 0.f) + 1.1920929e-07f);

    int lx = tid & 63, cy = tid >> 6;
    for (int cc = cy; cc < 64; cc += 4){
      float v = x[(size_t)b*DMODEL*L_SEQ + (size_t)(c0+cc)*L_SEQ + l0+lx];
      tile[cc][lx] = (v - mu)*istd;
    }
    __syncthreads();
    int cx = tid & 63, ly = tid >> 6;
    float w = gw[c0+cx], bb = gb[c0+cx];
    for (int ll = ly; ll < 64; ll += 4)
      t_out[((size_t)(b*L_SEQ) + l0+ll)*DMODEL + c0+cx] = tob(tile[cx][ll]*w + bb);
  }
}

// ---------------- in-proj GEMM 128x128, 512 thr (8 waves), XCD-swizzled ----------
__global__ __launch_bounds__(512) void gemm_inproj(const bf16* __restrict__ A, const bf16* __restrict__ B,
                                                   bf16* __restrict__ z, bf16* __restrict__ xbc,
                                                   float* __restrict__ dtb,
                                                   const float* __restrict__ db0, const float* __restrict__ db1){
  __shared__ __align__(16) bf16 lds[2][(128+128)*40];
  const int lda = DMODEL, ldb = DMODEL, N = DPROJ;
  int dir = blockIdx.z;
  const bf16* Bd = B + (size_t)dir*(size_t)N*ldb;
  int orig = blockIdx.x;
  int swz = (orig & 7)*76 + (orig >> 3);
  int m0 = (swz & 31)*128;
  int n0 = (swz >> 5)*128;
  int t = threadIdx.x;
  int wave = t >> 6, lane = t & 63;
  int wm = (wave & 1)*64, wn = (wave >> 1)*32;
  int lrow = lane & 15, quad = lane >> 4, lk8 = quad*8;

  int rA = t >> 2, oA = (t & 3)*8;
  int amA = m0 + rA;
  if (dir) amA = (amA & ~(L_SEQ-1)) | ((L_SEQ-1) - (amA & (L_SEQ-1)));
  int bnA = n0 + rA; if (bnA > N-1) bnA = N-1;
  const bf16* Ap = A + (size_t)amA*lda + oA;
  const bf16* Bp = Bd + (size_t)bnA*ldb + oA;

  f32x4_t acc[4][2];
  #pragma unroll
  for (int i = 0; i < 4; ++i){ acc[i][0] = (f32x4_t){0,0,0,0}; acc[i][1] = (f32x4_t){0,0,0,0}; }

  int nit = 8;
  uint4 a0 = *(const uint4*)Ap;
  uint4 b0 = *(const uint4*)Bp;
  int st = 0;
  *(uint4*)&lds[0][rA*40 + oA] = a0;
  *(uint4*)&lds[0][(128 + rA)*40 + oA] = b0;
  __syncthreads();
  for (int it = 0; it < nit; ++it){
    bool more = (it+1 < nit);
    if (more){
      int kk = (it+1) << 5;
      a0 = *(const uint4*)(Ap + kk);
      b0 = *(const uint4*)(Bp + kk);
    }
    const bf16* cs = lds[st];
    bf16x8_t bfr[2];
    #pragma unroll
    for (int ni = 0; ni < 2; ++ni) bfr[ni] = *(const bf16x8_t*)&cs[(128 + wn + ni*16 + lrow)*40 + lk8];
    #pragma unroll
    for (int mi = 0; mi < 4; ++mi){
      bf16x8_t af = *(const bf16x8_t*)&cs[(wm + mi*16 + lrow)*40 + lk8];
      #pragma unroll
      for (int ni = 0; ni < 2; ++ni)
        acc[mi][ni] = __builtin_amdgcn_mfma_f32_16x16x32_bf16(af, bfr[ni], acc[mi][ni], 0, 0, 0);
    }
    if (more){
      st ^= 1;
      *(uint4*)&lds[st][rA*40 + oA] = a0;
      *(uint4*)&lds[st][(128 + rA)*40 + oA] = b0;
      __syncthreads();
    }
  }

  if (n0 < DINNER + CONVDIM){
    __syncthreads();
    __bf16* outs = (__bf16*)lds;
    #pragma unroll
    for (int mi = 0; mi < 4; ++mi)
      #pragma unroll
      for (int ni = 0; ni < 2; ++ni)
        #pragma unroll
        for (int r = 0; r < 4; ++r)
          outs[(wm + mi*16 + quad*4 + r)*132 + wn + ni*16 + lrow] = (__bf16)acc[mi][ni][r];
    __syncthreads();
    bf16* dst; int ldd, c0;
    if (n0 < DINNER){ dst = z   + (size_t)dir*M_TOT*DINNER;  ldd = DINNER;  c0 = n0; }
    else            { dst = xbc + (size_t)dir*M_TOT*CONVDIM; ldd = CONVDIM; c0 = n0 - DINNER; }
    #pragma unroll
    for (int itv = 0; itv < 4; ++itv){
      int v = t + itv*512;
      int row = v >> 4, cb = v & 15;
      *(bf16x8_t*)&dst[(size_t)(m0+row)*ldd + c0 + cb*8] =
          *(const bf16x8_t*)&outs[row*132 + cb*8];
    }
  } else {
    const float* db = dir ? db1 : db0;
    float* dtp = dtb + (size_t)dir*((size_t)M_TOT*NH);
    #pragma unroll
    for (int mi = 0; mi < 4; ++mi)
      #pragma unroll
      for (int ni = 0; ni < 2; ++ni)
        #pragma unroll
        for (int r = 0; r < 4; ++r){
          int m = m0 + wm + mi*16 + quad*4 + r;
          int n = n0 + wn + ni*16 + lrow;
          if (n < N){
            int h = n - (DINNER + CONVDIM);
            float xx = acc[mi][ni][r] + db[h];
            dtp[(size_t)m*NH + h] = (xx > 20.f) ? xx : log1pf(expf(xx));
          }
        }
  }
}

// ---------------- fused final GEMM + epilogue, BK=64, prefetch-2 -----------------
__global__ __launch_bounds__(256) void gemm_final(const bf16* __restrict__ y, const bf16* __restrict__ tb,
                                                  const bf16* __restrict__ W, const bf16* __restrict__ psum,
                                                  const float* __restrict__ x, const float* __restrict__ pb,
                                                  float* __restrict__ out){
  __shared__ __align__(16) bf16 lds[2][(32+64)*72];
  __shared__ float tile[32][65];
  int orig = blockIdx.x;
  int swz = (orig & 7)*64 + (orig >> 3);   // 512 = 8*64, bijective
  int mt_ = swz & 127, nt_ = swz >> 7;
  int m0 = mt_*32, n0 = nt_*64;
  int t = threadIdx.x;
  int wave = t >> 6, lane = t & 63;
  int lrow = lane & 15, quad = lane >> 4, lk8 = quad*8;
  int wn = wave*16;

  f32x4_t acc[2];
  acc[0] = (f32x4_t){0,0,0,0}; acc[1] = (f32x4_t){0,0,0,0};

  int rowA = t >> 3, oA = (t & 7)*8;
  int rowB0 = t >> 3, oB0 = (t & 7)*8;
  int rowB1 = (t + 256) >> 3, oB1 = (t & 7)*8;

  #pragma unroll
  for (int ph = 0; ph < 3; ++ph){
    const bf16 *Ab, *Bb; int lda, ldb, K, rev;
    if (ph == 0){ Ab = y;                             lda = DINNER; K = DINNER; Bb = W;                             ldb = DINNER; rev = 0; }
    else if (ph == 1){ Ab = y + (size_t)M_TOT*DINNER; lda = DINNER; K = DINNER; Bb = W + (size_t)DMODEL*DINNER;     ldb = DINNER; rev = 1; }
    else { Ab = tb; lda = DMODEL; K = DMODEL; Bb = psum; ldb = DMODEL; rev = 0; }

    int am = m0 + rowA;
    if (rev) am = (am & ~(L_SEQ-1)) | ((L_SEQ-1) - (am & (L_SEQ-1)));
    const bf16* Ap  = Ab + (size_t)am*lda + oA;
    const bf16* Bp0 = Bb + (size_t)(n0 + rowB0)*ldb + oB0;
    const bf16* Bp1 = Bb + (size_t)(n0 + rowB1)*ldb + oB1;

    int nit = K >> 6;
    uint4 au  = *(const uint4*)Ap;
    uint4 bu0 = *(const uint4*)Bp0;
    uint4 bu1 = *(const uint4*)Bp1;
    uint4 av  = *(const uint4*)(Ap + 64);
    uint4 bv0 = *(const uint4*)(Bp0 + 64);
    uint4 bv1 = *(const uint4*)(Bp1 + 64);

#define FSTAGE(buf, A_, B0_, B1_) \
    *(uint4*)&lds[buf][rowA*72 + oA] = A_; \
    *(uint4*)&lds[buf][(32 + rowB0)*72 + oB0] = B0_; \
    *(uint4*)&lds[buf][(32 + rowB1)*72 + oB1] = B1_;

#define FCOMP(buf) { \
    const bf16* cs = lds[buf]; \
    _Pragma("unroll") \
    for (int ks = 0; ks < 2; ++ks){ \
      bf16x8_t bq = *(const bf16x8_t*)&cs[(32 + wn + lrow)*72 + ks*32 + lk8]; \
      _Pragma("unroll") \
      for (int mt = 0; mt < 2; ++mt){ \
        bf16x8_t af = *(const bf16x8_t*)&cs[(mt*16 + lrow)*72 + ks*32 + lk8]; \
        acc[mt] = __builtin_amdgcn_mfma_f32_16x16x32_bf16(af, bq, acc[mt], 0, 0, 0); \
      } \
    } }

    __syncthreads();
    FSTAGE(0, au, bu0, bu1)
    __syncthreads();
    for (int it = 0; it < nit; it += 2){
      if (it + 2 < nit){
        int kk = (it+2) << 6;
        au = *(const uint4*)(Ap+kk); bu0 = *(const uint4*)(Bp0+kk); bu1 = *(const uint4*)(Bp1+kk);
      }
      FCOMP(0)
      FSTAGE(1, av, bv0, bv1)
      __syncthreads();
      if (it + 3 < nit){
        int kk = (it+3) << 6;
        av = *(const uint4*)(Ap+kk); bv0 = *(const uint4*)(Bp0+kk); bv1 = *(const uint4*)(Bp1+kk);
      }
      FCOMP(1)
      if (it + 2 < nit){
        FSTAGE(0, au, bu0, bu1)
        __syncthreads();
      }
    }
#undef FSTAGE
#undef FCOMP
  }

  #pragma unroll
  for (int mt = 0; mt < 2; ++mt)
    #pragma unroll
    for (int r = 0; r < 4; ++r)
      tile[mt*16 + quad*4 + r][wn + lrow] = acc[mt][r];
  __syncthreads();
  int b = m0 >> 11, l0 = m0 & (L_SEQ-1);
  int tx = t & 31, ny = t >> 5;
  for (int nn = ny; nn < 64; nn += 8){
    int n = n0 + nn;
    size_t xi = (size_t)b*DMODEL*L_SEQ + (size_t)n*L_SEQ + l0 + tx;
    out[xi] = tile[tx][nn] + pb[n] + x[xi];
  }
}

// ---------------- depthwise causal conv + SiLU, vectorized rolling window --------
__global__ __launch_bounds__(256) void k_conv(const bf16* __restrict__ xraw, const float* __restrict__ cw0,
                                              const float* __restrict__ cb0, const float* __restrict__ cw1,
                                              const float* __restrict__ cb1, bf16* __restrict__ xconv){
  int t = threadIdx.x;
  int tx = t & 31, ty = t >> 5;
  int ch0 = blockIdx.x*256 + tx*8;
  int z = blockIdx.z; int b = z & 1, dir = z >> 1;
  int lbase = blockIdx.y*32 + ty*4;
  const float* cw = dir ? cw1 : cw0;
  const float* cb = dir ? cb1 : cb0;
  const bf16* xr = xraw  + (size_t)dir*((size_t)M_TOT*CONVDIM) + (size_t)(b*L_SEQ)*CONVDIM + ch0;
  bf16* xcv      = xconv + (size_t)dir*((size_t)M_TOT*CONVDIM) + (size_t)(b*L_SEQ)*CONVDIM + ch0;

  float wk[4][8];
  #pragma unroll
  for (int c = 0; c < 8; ++c){
    float4 w = *(const float4*)&cw[(ch0+c)*4];
    wk[0][c] = w.x; wk[1][c] = w.y; wk[2][c] = w.z; wk[3][c] = w.w;
  }
  float bias[8];
  {
    float4 b0v = *(const float4*)&cb[ch0];
    float4 b1v = *(const float4*)&cb[ch0+4];
    bias[0]=b0v.x; bias[1]=b0v.y; bias[2]=b0v.z; bias[3]=b0v.w;
    bias[4]=b1v.x; bias[5]=b1v.y; bias[6]=b1v.z; bias[7]=b1v.w;
  }

  bf16x8_t zero;
  #pragma unroll
  for (int c = 0; c < 8; ++c) zero[c] = (__bf16)0.f;

  bf16x8_t win[4];
  #pragma unroll
  for (int k = 0; k < 3; ++k){
    int ls = lbase - 3 + k;
    win[k] = (ls >= 0) ? *(const bf16x8_t*)&xr[(size_t)ls*CONVDIM] : zero;
  }
  #pragma unroll
  for (int i = 0; i < 4; ++i){
    int l = lbase + i;
    win[3] = *(const bf16x8_t*)&xr[(size_t)l*CONVDIM];
    bf16x8_t outv;
    #pragma unroll
    for (int c = 0; c < 8; ++c){
      float a = bias[c] + (float)win[0][c]*wk[0][c] + (float)win[1][c]*wk[1][c]
                        + (float)win[2][c]*wk[2][c] + (float)win[3][c]*wk[3][c];
      outv[c] = (__bf16)(a / (1.f + __expf(-a)));
    }
    *(bf16x8_t*)&xcv[(size_t)l*CONVDIM] = outv;
    win[0] = win[1]; win[1] = win[2]; win[2] = win[3];
  }
}

// ---------------- merged: per-chunk states+scan (0-511) | CB GEMM (512-1023) -----
__global__ __launch_bounds__(256) void k_states_cb(const bf16* __restrict__ xconv, const float* __restrict__ dt,
                                                   const float* __restrict__ Al0, const float* __restrict__ Al1,
                                                   float* __restrict__ A_cs, float* __restrict__ states,
                                                   bf16* __restrict__ CB){
  __shared__ __align__(16) char smem[34816];
  int bz = blockIdx.x, t = threadIdx.x;
  if (bz < 512){
    float* s_acs = (float*)smem;
    float* w_s   = (float*)(smem + 1024);
    __bf16* Xt   = (__bf16*)(smem + 2048);
    __bf16* Bt   = (__bf16*)(smem + 2048 + 9216);
    int id0 = bz;
    int dir = id0 >> 8; int id = id0 & 255;
    int h = id & 15; int bc = id >> 4; int ch = bc & 7; int b = bc >> 3;
    const bf16* xc = xconv + (size_t)dir*((size_t)M_TOT*CONVDIM);
    const float* dtp = dt + (size_t)dir*((size_t)M_TOT*NH);
    const float* Alog = dir ? Al1 : Al0;
    size_t rowbase = (size_t)(b*L_SEQ) + ch*CT;

    float dtv = dtp[(rowbase + t)*NH + h];
    s_acs[t] = -expf(Alog[h]) * dtv;
    __syncthreads();
    for (int off = 1; off < 256; off <<= 1){
      float v = (t >= off) ? s_acs[t-off] : 0.f;
      __syncthreads();
      s_acs[t] += v;
      __syncthreads();
    }
    A_cs[(size_t)dir*ACS_N + (size_t)((b*NH+h)*NCHK + ch)*CT + t] = s_acs[t];
    float alast = s_acs[CT-1];
    w_s[t] = dtv * __expf(fminf(alast - s_acs[t], 0.f));
    __syncthreads();

    int wave = t >> 6, lane = t & 63, lrow = lane & 15, quad = lane >> 4;
    f32x4_t acc[8];
    #pragma unroll
    for (int i = 0; i < 8; ++i) acc[i] = (f32x4_t){0.f,0.f,0.f,0.f};

    for (int kt = 0; kt < 4; ++kt){
      int l0 = kt*64;
      #pragma unroll
      for (int it = 0; it < 2; ++it){
        int idx = t + it*256; int l = idx >> 3; int p0 = (idx & 7)*8;
        bf16x8_t v = *(const bf16x8_t*)&xc[(rowbase + l0 + l)*CONVDIM + h*HD + p0];
        float w = w_s[l0 + l];
        int col = (((l>>3) ^ ((p0>>3)&7))<<3) | (l&7);
        #pragma unroll
        for (int j = 0; j < 8; ++j) Xt[(p0+j)*72 + col] = (__bf16)((float)v[j]*w);
      }
      #pragma unroll
      for (int it = 0; it < 4; ++it){
        int idx = t + it*256; int l = idx >> 4; int n0 = (idx & 15)*8;
        bf16x8_t v = *(const bf16x8_t*)&xc[(rowbase + l0 + l)*CONVDIM + DINNER + n0];
        int col = (((l>>3) ^ ((n0>>3)&7))<<3) | (l&7);
        #pragma unroll
        for (int j = 0; j < 8; ++j) Bt[(n0+j)*72 + col] = v[j];
      }
      __syncthreads();
      int arow = wave*16 + lrow;
      #pragma unroll
      for (int ks = 0; ks < 2; ++ks){
        int kg = ks*4 + quad;
        bf16x8_t af = *(const bf16x8_t*)&Xt[arow*72 + ((kg ^ ((arow>>3)&7))<<3)];
        #pragma unroll
        for (int nt = 0; nt < 8; ++nt){
          int brow = nt*16 + lrow;
          bf16x8_t bq = *(const bf16x8_t*)&Bt[brow*72 + ((kg ^ ((brow>>3)&7))<<3)];
          acc[nt] = __builtin_amdgcn_mfma_f32_16x16x32_bf16(af, bq, acc[nt], 0, 0, 0);
        }
      }
      __syncthreads();
    }
    float* so = states + (size_t)dir*ST_N + (size_t)id*HD*DSTATE;
    int m = wave*16 + quad*4;
    #pragma unroll
    for (int nt = 0; nt < 8; ++nt)
      #pragma unroll
      for (int r = 0; r < 4; ++r)
        so[(size_t)(m+r)*DSTATE + nt*16 + lrow] = acc[nt][r];
  } else {
    __bf16* As = (__bf16*)smem;
    __bf16* Bs = (__bf16*)(smem + 17408);
    int sub = bz - 512;
    int zz = sub >> 4;
    int dir = zz >> 4; int b = (zz >> 3) & 1; int ch = zz & 7;
    int rest = sub & 15;
    int m0 = (rest >> 2)*64, n0 = (rest & 3)*64;
    if (n0 > m0) return;
    const bf16* base = xconv + (size_t)dir*((size_t)M_TOT*CONVDIM) + (size_t)(b*L_SEQ + ch*CT)*CONVDIM;
    const bf16* Crow = base + DINNER + DSTATE;
    const bf16* Brow = base + DINNER;
    int r = t >> 2, o0 = (t & 3)*32;
    #pragma unroll
    for (int j = 0; j < 4; ++j){
      *(bf16x8_t*)&As[r*136 + o0 + j*8] = *(const bf16x8_t*)&Crow[(size_t)(m0+r)*CONVDIM + o0 + j*8];
      *(bf16x8_t*)&Bs[r*136 + o0 + j*8] = *(const bf16x8_t*)&Brow[(size_t)(n0+r)*CONVDIM + o0 + j*8];
    }
    __syncthreads();
    int wave = t >> 6, lane = t & 63, lrow = lane & 15, quad = lane >> 4;
    int wm = wave*16;
    f32x4_t acc[4];
    #pragma unroll
    for (int i = 0; i < 4; ++i) acc[i] = (f32x4_t){0.f,0.f,0.f,0.f};
    #pragma unroll
    for (int ks = 0; ks < 4; ++ks){
      bf16x8_t af = *(const bf16x8_t*)&As[(wm+lrow)*136 + ks*32 + quad*8];
      #pragma unroll
      for (int nt = 0; nt < 4; ++nt){
        bf16x8_t bq = *(const bf16x8_t*)&Bs[(nt*16+lrow)*136 + ks*32 + quad*8];
        acc[nt] = __builtin_amdgcn_mfma_f32_16x16x32_bf16(af, bq, acc[nt], 0, 0, 0);
      }
    }
    __syncthreads();
    #pragma unroll
    for (int nt = 0; nt < 4; ++nt)
      #pragma unroll
      for (int r2 = 0; r2 < 4; ++r2)
        As[(wm + quad*4 + r2)*72 + nt*16 + lrow] = (__bf16)acc[nt][r2];
    __syncthreads();
    bf16* outp = CB + (size_t)dir*CB_N + (size_t)(b*NCHK+ch)*CT*CT;
    #pragma unroll
    for (int p = 0; p < 2; ++p){
      int idx = t + p*256;
      int row = idx >> 3, c8 = (idx & 7)*8;
      *(bf16x8_t*)&outp[(size_t)(m0+row)*CT + n0 + c8] = *(const bf16x8_t*)&As[row*72 + c8];
    }
  }
}

// ---------------- inter-chunk recurrence: emits bf16 prefix states ---------------
__global__ __launch_bounds__(256) void k_recur(const float* __restrict__ states, bf16* __restrict__ nsb,
                                               const float* __restrict__ A_cs){
  int blk = blockIdx.x;
  int bh2 = blk >> 5;
  int e = (blk & 31)*256 + threadIdx.x;
  int dir = bh2 >> 5; int bh = bh2 & 31;
  int h = bh & 15, b = bh >> 4;
  const float* ac = A_cs + (size_t)dir*ACS_N;
  const float* st = states + (size_t)dir*ST_N;
  bf16* nb = nsb + (size_t)dir*ST_N;
  float s = 0.f;
  #pragma unroll
  for (int ch = 0; ch < NCHK; ++ch){
    float dec = expdec(ac[((size_t)(bh*NCHK+ch))*CT + CT-1]);
    size_t off = (size_t)(((b*NCHK+ch)*NH)+h)*HD*DSTATE + e;
    float cur = st[off];
    nb[off] = tob(s);
    s = s*dec + cur;
  }
}

// ---------------- Y = (L*CB)@X + exp(Acs)*(C@NS)  (MFMA, merged-hh 512 thr) ------
__global__ __launch_bounds__(512) void k_y_mfma(const bf16* __restrict__ xconv, const float* __restrict__ dt,
                                                const float* __restrict__ A_cs, const bf16* __restrict__ CB,
                                                const bf16* __restrict__ ns, bf16* __restrict__ y){
  int id0 = blockIdx.x;
  int dir = id0 >> 8; int id = id0 & 255;
  int h = id & 15; int bc = id >> 4; int ch = bc & 7; int b = bc >> 3;
  int t = threadIdx.x;
  int lane = t & 63;
  int lrow = lane & 15, quad = lane >> 4;

  __shared__ __align__(16) bf16 Xs[64*264];
  __shared__ __align__(16) bf16 NSs[64*136];
  __shared__ float acs_s[CT];

  const bf16* xc = xconv + (size_t)dir*((size_t)M_TOT*CONVDIM);
  const float* dtp = dt + (size_t)dir*((size_t)M_TOT*NH);
  const float* acs = A_cs + (size_t)dir*ACS_N + (size_t)((b*NH+h)*NCHK + ch)*CT;
  const bf16* cbz = CB + (size_t)dir*CB_N + (size_t)(b*NCHK+ch)*CT*CT;
  const bf16* nsp = ns + (size_t)dir*ST_N + (size_t)(((b*NCHK+ch)*NH)+h)*HD*DSTATE;
  bf16* yp = y + (size_t)dir*((size_t)M_TOT*DINNER);
  size_t rowbase = (size_t)(b*L_SEQ + ch*CT);
  if (t < CT) acs_s[t] = acs[t];

  #pragma unroll
  for (int it = 0; it < 4; ++it){
    int idx = t + it*512;
    int s = idx >> 3, p0 = (idx & 7)*8;
    float dtv = dtp[(rowbase + s)*NH + h];
    bf16x8_t v = *(const bf16x8_t*)&xc[(rowbase + s)*CONVDIM + h*HD + p0];
    int col = ((((s>>3) ^ ((p0>>3)&7)))<<3) | (s&7);
    #pragma unroll
    for (int j = 0; j < 8; ++j)
      Xs[(p0+j)*264 + col] = tob((float)v[j] * dtv);
  }
  #pragma unroll
  for (int it = 0; it < 2; ++it){
    int idx = t + it*512;
    int p = idx >> 4, n8 = (idx & 15)*8;
    *(bf16x8_t*)&NSs[p*136 + n8] = *(const bf16x8_t*)&nsp[(size_t)p*DSTATE + n8];
  }
  __syncthreads();

  int wave = t >> 6;           // [0,8)
  int row0 = wave*32;
  float al0 = acs_s[row0 + lrow];
  float al1 = acs_s[row0 + 16 + lrow];
  float acs_r0 = acs_s[row0];

  f32x4_t acc[2][4];
  #pragma unroll
  for (int i = 0; i < 2; ++i)
    #pragma unroll
    for (int j = 0; j < 4; ++j) acc[i][j] = (f32x4_t){0.f,0.f,0.f,0.f};

  int nst = (row0 + 32) >> 5;
  for (int st = 0; st < nst; ++st){
    int s0 = st*32;
    if (s0 + 31 < row0 && (acs_r0 - acs_s[s0+31]) < -30.f) continue;
    int sg = (s0 >> 3) + quad;
    bf16x8_t bq[4];
    #pragma unroll
    for (int nt = 0; nt < 4; ++nt){
      int brow = nt*16 + lrow;
      bq[nt] = *(const bf16x8_t*)&Xs[brow*264 + ((sg ^ ((brow>>3)&7))<<3)];
    }
    bf16x8_t af[2];
    #pragma unroll
    for (int mt = 0; mt < 2; ++mt){
      int l = row0 + mt*16 + lrow;
      float al = mt ? al1 : al0;
      bf16x8_t cvv = *(const bf16x8_t*)&cbz[(size_t)l*CT + s0 + quad*8];
      union { bf16x8_t v; __bf16 e[8]; } wa;
      #pragma unroll
      for (int j = 0; j < 8; ++j){
        int s = s0 + quad*8 + j;
        float w = (s <= l) ? __expf(fminf(al - acs_s[s], 0.f)) * (float)cvv[j] : 0.f;
        wa.e[j] = (__bf16)w;
      }
      af[mt] = wa.v;
    }
    #pragma unroll
    for (int mt = 0; mt < 2; ++mt)
      #pragma unroll
      for (int nt = 0; nt < 4; ++nt)
        acc[mt][nt] = __builtin_amdgcn_mfma_f32_16x16x32_bf16(af[mt], bq[nt], acc[mt][nt], 0, 0, 0);
  }

  float el0 = __expf(fminf(al0, 0.f));
  float el1 = __expf(fminf(al1, 0.f));
  #pragma unroll
  for (int kt = 0; kt < 4; ++kt){
    int n0 = kt*32;
    bf16x8_t bq[4];
    #pragma unroll
    for (int nt = 0; nt < 4; ++nt)
      bq[nt] = *(const bf16x8_t*)&NSs[(nt*16+lrow)*136 + n0 + quad*8];
    bf16x8_t af[2];
    #pragma unroll
    for (int mt = 0; mt < 2; ++mt){
      int l = row0 + mt*16 + lrow;
      float el = mt ? el1 : el0;
      union { bf16x8_t v; __bf16 e[8]; } cu;
      cu.v = *(const bf16x8_t*)&xc[(rowbase + l)*CONVDIM + DINNER + DSTATE + n0 + quad*8];
      union { bf16x8_t v; __bf16 e[8]; } wa;
      #pragma unroll
      for (int j = 0; j < 8; ++j) wa.e[j] = (__bf16)((float)cu.e[j] * el);
      af[mt] = wa.v;
    }
    #pragma unroll
    for (int mt = 0; mt < 2; ++mt)
      #pragma unroll
      for (int nt = 0; nt < 4; ++nt)
        acc[mt][nt] = __builtin_amdgcn_mfma_f32_16x16x32_bf16(af[mt], bq[nt], acc[mt][nt], 0, 0, 0);
  }

  #pragma unroll
  for (int mt = 0; mt < 2; ++mt)
    #pragma unroll
    for (int nt = 0; nt < 4; ++nt)
      #pragma unroll
      for (int rr = 0; rr < 4; ++rr){
        int l = row0 + mt*16 + quad*4 + rr;
        int p = nt*16 + lrow;
        yp[(rowbase + l)*DINNER + h*HD + p] = tob(acc[mt][nt][rr]);
      }
}

// ---------------- gate ((y + D*x) * silu(z)) + RMSNorm, vectorized ---------------
__global__ __launch_bounds__(256) void k_gaterms(const bf16* __restrict__ z, const float* __restrict__ nw0,
                                                 const float* __restrict__ nw1, const bf16* __restrict__ xconv,
                                                 const float* __restrict__ Dh0, const float* __restrict__ Dh1,
                                                 bf16* __restrict__ y){
  int m0 = blockIdx.x;
  int dir = m0 >> 12; int m = m0 & (M_TOT-1);
  int t = threadIdx.x;
  const float* nw = dir ? nw1 : nw0;
  const float* Dh = dir ? Dh1 : Dh0;
  int j0 = t*4;
  const bf16* zp = z + (size_t)dir*((size_t)M_TOT*DINNER) + (size_t)m*DINNER;
  const bf16* xc = xconv + (size_t)dir*((size_t)M_TOT*CONVDIM) + (size_t)m*CONVDIM;
  bf16* yp = y + (size_t)dir*((size_t)M_TOT*DINNER) + (size_t)m*DINNER;

  bf16x4_t zv = *(const bf16x4_t*)&zp[j0];
  bf16x4_t yv = *(const bf16x4_t*)&yp[j0];
  bf16x4_t xv = *(const bf16x4_t*)&xc[j0];
  float Dv = Dh[j0 >> 6];
  float v[4]; float ss = 0.f;
  #pragma unroll
  for (int c = 0; c < 4; ++c){
    float zf = (float)zv[c];
    float raw = (float)yv[c] + Dv*(float)xv[c];
    float g = raw * (zf / (1.f + __expf(-zf)));
    v[c] = g; ss += g*g;
  }
  for (int o = 32; o > 0; o >>= 1) ss += __shfl_down(ss, o, 64);
  __shared__ float sh[4];
  if ((t & 63) == 0) sh[t>>6] = ss;
  __syncthreads();
  ss = sh[0]+sh[1]+sh[2]+sh[3];
  float scale = rsqrtf(ss*(1.f/DINNER) + 1e-5f);
  float4 nwv = *(const float4*)&nw[j0];
  float nws[4] = {nwv.x, nwv.y, nwv.z, nwv.w};
  bf16x4_t o;
  #pragma unroll
  for (int c = 0; c < 4; ++c) o[c] = (__bf16)(v[c]*scale*nws[c]);
  *(bf16x4_t*)&yp[j0] = o;
}

extern "C" void kernel_launch(void* const* d_in, const int* in_sizes, int n_in,
                              void* d_out, int out_size, void* d_ws, size_t ws_size,
                              hipStream_t stream){
  (void)in_sizes; (void)n_in; (void)out_size; (void)ws_size;
  const float* x      = (const float*)d_in[0];
  const float* gn_w   = (const float*)d_in[1];
  const float* gn_b   = (const float*)d_in[2];
  const float* proj_w = (const float*)d_in[3];
  const float* proj_b = (const float*)d_in[4];
  float* out = (float*)d_out;

  char* wp = (char*)d_ws;
  auto alloc = [&](size_t bytes){ void* r = (void*)wp; wp += (bytes + 255) & ~(size_t)255; return r; };
  bf16*  t_buf  = (bf16*) alloc((size_t)M_TOT*DMODEL*2);
  bf16*  z_buf  = (bf16*) alloc((size_t)2*M_TOT*DINNER*2);
  bf16*  xraw   = (bf16*) alloc((size_t)2*M_TOT*CONVDIM*2);   // reused as y (both dirs)
  bf16*  xconv  = (bf16*) alloc((size_t)2*M_TOT*CONVDIM*2);
  float* dt_buf = (float*)alloc((size_t)2*M_TOT*NH*4);
  float* acs    = (float*)alloc((size_t)2*ACS_N*4);
  float* states = (float*)alloc((size_t)2*ST_N*4);
  bf16*  nsb    = (bf16*) alloc((size_t)2*ST_N*2);
  bf16*  cb     = (bf16*) alloc((size_t)2*CB_N*2);
  float2* pbuf  = (float2*)alloc(BATCH*128*sizeof(float2));
  bf16*  inw_bf   = (bf16*)alloc((size_t)2*DPROJ*DMODEL*2);
  bf16*  projw_bf = (bf16*)alloc((size_t)DMODEL*2*DMODEL*2);
  bf16*  owt      = (bf16*)alloc((size_t)2*DINNER*DMODEL*2);
  bf16*  wfb      = (bf16*)alloc((size_t)2*DMODEL*DINNER*2);
  bf16*  psum     = (bf16*)alloc((size_t)DMODEL*DMODEL*2);
  bf16*  y_buf    = xraw;   // xraw dead after conv

  k_front<<<1704, 256, 0, stream>>>(
      (const float*)d_in[5], (const float*)d_in[13], proj_w,
      inw_bf, projw_bf,
      (const float*)d_in[12], (const float*)d_in[20], owt, psum,
      x, pbuf);

  k_wt<<<320, 256, 0, stream>>>(projw_bf, owt, wfb, x, gn_w, gn_b, pbuf, t_buf);

  gemm_inproj<<<dim3(608, 1, 2), 512, 0, stream>>>(
      t_buf, inw_bf, z_buf, xraw, dt_buf,
      (const float*)d_in[8], (const float*)d_in[16]);

  k_conv<<<dim3(5, L_SEQ/32, 2*BATCH), 256, 0, stream>>>(
      xraw, (const float*)d_in[6], (const float*)d_in[7],
            (const float*)d_in[14], (const float*)d_in[15], xconv);
  k_states_cb<<<1024, 256, 0, stream>>>(
      xconv, dt_buf, (const float*)d_in[9], (const float*)d_in[17], acs, states, cb);
  k_recur<<<2*BATCH*NH*32, 256, 0, stream>>>(states, nsb, acs);
  k_y_mfma<<<2*BATCH*NCHK*NH, 512, 0, stream>>>(xconv, dt_buf, acs, cb, nsb, y_buf);
  k_gaterms<<<2*M_TOT, 256, 0, stream>>>(
      z_buf, (const float*)d_in[11], (const float*)d_in[19], xconv,
      (const float*)d_in[10], (const float*)d_in[18], y_buf);

  gemm_final<<<512, 256, 0, stream>>>(y_buf, t_buf, wfb, psum, x, proj_b, out);
}

// Round 16
// 202.725 us; speedup vs baseline: 1.3907x; 1.0216x over previous
//
#include <hip/hip_runtime.h>
#include <hip/hip_bf16.h>
#include <math.h>

using bf16 = __hip_bfloat16;

#define L_SEQ   2048
#define DMODEL  256
#define DINNER  1024
#define DSTATE  128
#define NH      16
#define HD      64
#define CONVDIM 1280
#define DPROJ   2320
#define NCHK    8
#define CT      256
#define BATCH   2
#define M_TOT   (BATCH*L_SEQ)

#define ACS_N   (BATCH*NH*NCHK*CT)
#define ST_N    ((size_t)BATCH*NCHK*NH*HD*DSTATE)
#define CB_N    ((size_t)BATCH*NCHK*CT*CT)

typedef __bf16 bf16x8_t __attribute__((ext_vector_type(8)));
typedef __bf16 bf16x4_t __attribute__((ext_vector_type(4)));
typedef float  f32x4_t  __attribute__((ext_vector_type(4)));

__device__ __forceinline__ float tof(bf16 v){ return __bfloat162float(v); }
__device__ __forceinline__ bf16  tob(float v){ return __float2bfloat16(v); }
__device__ __forceinline__ float expdec(float a){ return __expf(fminf(a, 0.f)); }

// ---------------- front mega-kernel: weight casts + owt/psum prep + batch stats --
__global__ __launch_bounds__(256) void k_front(
    const float* __restrict__ iw0, const float* __restrict__ iw1, const float* __restrict__ pw,
    bf16* __restrict__ inw_bf, bf16* __restrict__ projw_bf,
    const float* __restrict__ ow0, const float* __restrict__ ow1,
    bf16* __restrict__ owt, bf16* __restrict__ psum,
    const float* __restrict__ x, float2* __restrict__ pbuf){
  __shared__ __bf16 tile[64][65];
  __shared__ float sh[8];
  int bz = blockIdx.x, t = threadIdx.x;
  if (bz < 1160){
    int dir = bz >= 580; int sub = dir ? bz - 580 : bz;
    const float* src = dir ? iw1 : iw0;
    bf16* dst = inw_bf + (size_t)dir*DPROJ*DMODEL;
    int i = (sub*256 + t)*4;
    float4 v = *(const float4*)(src + i);
    dst[i]   = tob(v.x); dst[i+1] = tob(v.y);
    dst[i+2] = tob(v.z); dst[i+3] = tob(v.w);
  } else if (bz < 1288){
    int i = ((bz-1160)*256 + t)*4;
    float4 v = *(const float4*)(pw + i);
    projw_bf[i]   = tob(v.x); projw_bf[i+1] = tob(v.y);
    projw_bf[i+2] = tob(v.z); projw_bf[i+3] = tob(v.w);
  } else if (bz < 1416){
    int sub = bz - 1288;
    int dir = sub >> 6; int tid = sub & 63;
    int k0 = (tid >> 2)*64, j0 = (tid & 3)*64;
    const float* src = dir ? ow1 : ow0;
    bf16* dst = owt + (size_t)dir*DINNER*DMODEL;
    #pragma unroll
    for (int it = 0; it < 2; ++it){
      int idx = t + it*256; int jj = idx >> 3; int k8 = (idx & 7)*8;
      float4 va = *(const float4*)&src[(size_t)(j0+jj)*DINNER + k0 + k8];
      float4 vb = *(const float4*)&src[(size_t)(j0+jj)*DINNER + k0 + k8 + 4];
      tile[k8+0][jj] = (__bf16)va.x; tile[k8+1][jj] = (__bf16)va.y;
      tile[k8+2][jj] = (__bf16)va.z; tile[k8+3][jj] = (__bf16)va.w;
      tile[k8+4][jj] = (__bf16)vb.x; tile[k8+5][jj] = (__bf16)vb.y;
      tile[k8+6][jj] = (__bf16)vb.z; tile[k8+7][jj] = (__bf16)vb.w;
    }
    __syncthreads();
    #pragma unroll
    for (int it = 0; it < 2; ++it){
      int idx = t + it*256; int kr = idx >> 3; int j8 = (idx & 7)*8;
      bf16x8_t o;
      #pragma unroll
      for (int i = 0; i < 8; ++i) o[i] = tile[kr][j8+i];
      *(bf16x8_t*)&dst[(size_t)(k0+kr)*DMODEL + j0 + j8] = o;
    }
  } else if (bz < 1448){
    int i = ((bz - 1416)*256 + t)*8;
    int j = i & 255;
    const float* row = pw + (size_t)(i >> 8)*(2*DMODEL);
    bf16x8_t o;
    #pragma unroll
    for (int c = 0; c < 8; ++c) o[c] = (__bf16)(row[j+c] + row[256+j+c]);
    *(bf16x8_t*)&psum[i] = o;
  } else {
    int sub = bz - 1448;
    int blk = sub & 127, b = sub >> 7;
    const float4* p = (const float4*)(x + (size_t)b*(DMODEL*L_SEQ) + (size_t)blk*4096);
    float s = 0.f, ss = 0.f;
    #pragma unroll
    for (int k = 0; k < 4; ++k){
      float4 v = p[t + k*256];
      s  += v.x + v.y + v.z + v.w;
      ss += v.x*v.x + v.y*v.y + v.z*v.z + v.w*v.w;
    }
    for (int o = 32; o > 0; o >>= 1){ s += __shfl_down(s, o, 64); ss += __shfl_down(ss, o, 64); }
    if ((t & 63) == 0){ sh[(t>>6)*2] = s; sh[(t>>6)*2+1] = ss; }
    __syncthreads();
    if (t == 0){
      s  = sh[0]+sh[2]+sh[4]+sh[6];
      ss = sh[1]+sh[3]+sh[5]+sh[7];
      pbuf[b*128 + blk] = make_float2(s, ss);
    }
  }
}

// ---------------- merged: W = P@owt (blocks 0-63) + GroupNorm/transpose (64-319) -
__global__ __launch_bounds__(256) void k_wt(const bf16* __restrict__ P, const bf16* __restrict__ owt,
                                            bf16* __restrict__ W,
                                            const float* __restrict__ x, const float* __restrict__ gw,
                                            const float* __restrict__ gb, const float2* __restrict__ pbuf,
                                            bf16* __restrict__ t_out){
  __shared__ __align__(16) bf16 lds[2][(128+64)*40];
  __shared__ float tile[64][65];
  __shared__ float sh[4];
  int bz6 = blockIdx.x;
  int t = threadIdx.x;
  if (bz6 < 64){
    int dir = bz6 & 1;
    int m0 = (bz6 >> 5)*128, n0 = ((bz6 >> 1) & 15)*64;
    int wave = t >> 6, lane = t & 63;
    int wm = (wave & 1)*64, wn = (wave >> 1)*32;
    int lrow = lane & 15, quad = lane >> 4, lk8 = quad*8;

    int r0 = t >> 2, o0 = (t & 3)*8;
    int r1 = r0 + 64;
    const bf16* Ap0 = P + (size_t)(m0 + r0)*(2*DMODEL) + dir*DMODEL + o0;
    const bf16* Ap1 = P + (size_t)(m0 + r1)*(2*DMODEL) + dir*DMODEL + o0;
    const bf16* Bp  = owt + (size_t)dir*DINNER*DMODEL + (size_t)(n0 + r0)*DMODEL + o0;

    f32x4_t acc[4][2];
    #pragma unroll
    for (int i = 0; i < 4; ++i){ acc[i][0] = (f32x4_t){0,0,0,0}; acc[i][1] = (f32x4_t){0,0,0,0}; }

    int nit = DMODEL >> 5;  // 8
    uint4 a0 = *(const uint4*)Ap0;
    uint4 a1 = *(const uint4*)Ap1;
    uint4 b0 = *(const uint4*)Bp;
    int st = 0;
    *(uint4*)&lds[0][r0*40 + o0] = a0;
    *(uint4*)&lds[0][r1*40 + o0] = a1;
    *(uint4*)&lds[0][(128 + r0)*40 + o0] = b0;
    __syncthreads();
    for (int it = 0; it < nit; ++it){
      bool more = (it+1 < nit);
      if (more){
        int kk = (it+1) << 5;
        a0 = *(const uint4*)(Ap0 + kk);
        a1 = *(const uint4*)(Ap1 + kk);
        b0 = *(const uint4*)(Bp + kk);
      }
      const bf16* cs = lds[st];
      bf16x8_t af[4], bfr[2];
      #pragma unroll
      for (int mi = 0; mi < 4; ++mi) af[mi] = *(const bf16x8_t*)&cs[(wm + mi*16 + lrow)*40 + lk8];
      #pragma unroll
      for (int ni = 0; ni < 2; ++ni) bfr[ni] = *(const bf16x8_t*)&cs[(128 + wn + ni*16 + lrow)*40 + lk8];
      #pragma unroll
      for (int mi = 0; mi < 4; ++mi)
        #pragma unroll
        for (int ni = 0; ni < 2; ++ni)
          acc[mi][ni] = __builtin_amdgcn_mfma_f32_16x16x32_bf16(af[mi], bfr[ni], acc[mi][ni], 0, 0, 0);
      if (more){
        st ^= 1;
        *(uint4*)&lds[st][r0*40 + o0] = a0;
        *(uint4*)&lds[st][r1*40 + o0] = a1;
        *(uint4*)&lds[st][(128 + r0)*40 + o0] = b0;
        __syncthreads();
      }
    }
    bf16* Wd = W + (size_t)dir*DMODEL*DINNER;
    #pragma unroll
    for (int mi = 0; mi < 4; ++mi)
      #pragma unroll
      for (int ni = 0; ni < 2; ++ni)
        #pragma unroll
        for (int r = 0; r < 4; ++r){
          int m = m0 + wm + mi*16 + quad*4 + r;
          int n = n0 + wn + ni*16 + lrow;
          Wd[(size_t)m*DINNER + n] = tob(acc[mi][ni][r]);
        }
  } else {
    int sub = bz6 - 64;
    int l0 = (sub & 31)*64, c0 = ((sub >> 5) & 3)*64, b = sub >> 7;
    int tid = t;
    float s = 0.f, ss = 0.f;
    if (tid < 128){ float2 v = pbuf[b*128 + tid]; s = v.x; ss = v.y; }
    for (int o = 32; o > 0; o >>= 1){ s += __shfl_down(s, o, 64); ss += __shfl_down(ss, o, 64); }
    if (tid < 128 && (tid & 63) == 0){ sh[(tid>>6)*2] = s; sh[(tid>>6)*2+1] = ss; }
    __syncthreads();
    float inv = 1.f/(float)(DMODEL*L_SEQ);
    float s0 = sh[0]+sh[2], ss0 = sh[1]+sh[3];
    float mu = s0*inv, var = ss0*inv - mu*mu;
    float istd = rsqrtf(fmaxf(var, 0.f) + 1.1920929e-07f);

    int lx = tid & 63, cy = tid >> 6;
    for (int cc = cy; cc < 64; cc += 4){
      float v = x[(size_t)b*DMODEL*L_SEQ + (size_t)(c0+cc)*L_SEQ + l0+lx];
      tile[cc][lx] = (v - mu)*istd;
    }
    __syncthreads();
    int cx = tid & 63, ly = tid >> 6;
    float w = gw[c0+cx], bb = gb[c0+cx];
    for (int ll = ly; ll < 64; ll += 4)
      t_out[((size_t)(b*L_SEQ) + l0+ll)*DMODEL + c0+cx] = tob(tile[cx][ll]*w + bb);
  }
}

// ---------------- in-proj GEMM 128x128, 512 thr (8 waves), XCD-swizzled ----------
__global__ __launch_bounds__(512) void gemm_inproj(const bf16* __restrict__ A, const bf16* __restrict__ B,
                                                   bf16* __restrict__ z, bf16* __restrict__ xbc,
                                                   float* __restrict__ dtb,
                                                   const float* __restrict__ db0, const float* __restrict__ db1){
  __shared__ __align__(16) bf16 lds[2][(128+128)*40];
  const int lda = DMODEL, ldb = DMODEL, N = DPROJ;
  int dir = blockIdx.z;
  const bf16* Bd = B + (size_t)dir*(size_t)N*ldb;
  int orig = blockIdx.x;
  int swz = (orig & 7)*76 + (orig >> 3);
  int m0 = (swz & 31)*128;
  int n0 = (swz >> 5)*128;
  int t = threadIdx.x;
  int wave = t >> 6, lane = t & 63;
  int wm = (wave & 1)*64, wn = (wave >> 1)*32;
  int lrow = lane & 15, quad = lane >> 4, lk8 = quad*8;

  int rA = t >> 2, oA = (t & 3)*8;
  int amA = m0 + rA;
  if (dir) amA = (amA & ~(L_SEQ-1)) | ((L_SEQ-1) - (amA & (L_SEQ-1)));
  int bnA = n0 + rA; if (bnA > N-1) bnA = N-1;
  const bf16* Ap = A + (size_t)amA*lda + oA;
  const bf16* Bp = Bd + (size_t)bnA*ldb + oA;

  f32x4_t acc[4][2];
  #pragma unroll
  for (int i = 0; i < 4; ++i){ acc[i][0] = (f32x4_t){0,0,0,0}; acc[i][1] = (f32x4_t){0,0,0,0}; }

  int nit = 8;
  uint4 a0 = *(const uint4*)Ap;
  uint4 b0 = *(const uint4*)Bp;
  int st = 0;
  *(uint4*)&lds[0][rA*40 + oA] = a0;
  *(uint4*)&lds[0][(128 + rA)*40 + oA] = b0;
  __syncthreads();
  for (int it = 0; it < nit; ++it){
    bool more = (it+1 < nit);
    if (more){
      int kk = (it+1) << 5;
      a0 = *(const uint4*)(Ap + kk);
      b0 = *(const uint4*)(Bp + kk);
    }
    const bf16* cs = lds[st];
    bf16x8_t bfr[2];
    #pragma unroll
    for (int ni = 0; ni < 2; ++ni) bfr[ni] = *(const bf16x8_t*)&cs[(128 + wn + ni*16 + lrow)*40 + lk8];
    #pragma unroll
    for (int mi = 0; mi < 4; ++mi){
      bf16x8_t af = *(const bf16x8_t*)&cs[(wm + mi*16 + lrow)*40 + lk8];
      #pragma unroll
      for (int ni = 0; ni < 2; ++ni)
        acc[mi][ni] = __builtin_amdgcn_mfma_f32_16x16x32_bf16(af, bfr[ni], acc[mi][ni], 0, 0, 0);
    }
    if (more){
      st ^= 1;
      *(uint4*)&lds[st][rA*40 + oA] = a0;
      *(uint4*)&lds[st][(128 + rA)*40 + oA] = b0;
      __syncthreads();
    }
  }

  if (n0 < DINNER + CONVDIM){
    __syncthreads();
    __bf16* outs = (__bf16*)lds;
    #pragma unroll
    for (int mi = 0; mi < 4; ++mi)
      #pragma unroll
      for (int ni = 0; ni < 2; ++ni)
        #pragma unroll
        for (int r = 0; r < 4; ++r)
          outs[(wm + mi*16 + quad*4 + r)*132 + wn + ni*16 + lrow] = (__bf16)acc[mi][ni][r];
    __syncthreads();
    bf16* dst; int ldd, c0;
    if (n0 < DINNER){ dst = z   + (size_t)dir*M_TOT*DINNER;  ldd = DINNER;  c0 = n0; }
    else            { dst = xbc + (size_t)dir*M_TOT*CONVDIM; ldd = CONVDIM; c0 = n0 - DINNER; }
    #pragma unroll
    for (int itv = 0; itv < 4; ++itv){
      int v = t + itv*512;
      int row = v >> 4, cb = v & 15;
      *(bf16x8_t*)&dst[(size_t)(m0+row)*ldd + c0 + cb*8] =
          *(const bf16x8_t*)&outs[row*132 + cb*8];
    }
  } else {
    const float* db = dir ? db1 : db0;
    float* dtp = dtb + (size_t)dir*((size_t)M_TOT*NH);
    #pragma unroll
    for (int mi = 0; mi < 4; ++mi)
      #pragma unroll
      for (int ni = 0; ni < 2; ++ni)
        #pragma unroll
        for (int r = 0; r < 4; ++r){
          int m = m0 + wm + mi*16 + quad*4 + r;
          int n = n0 + wn + ni*16 + lrow;
          if (n < N){
            int h = n - (DINNER + CONVDIM);
            float xx = acc[mi][ni][r] + db[h];
            dtp[(size_t)m*NH + h] = (xx > 20.f) ? xx : log1pf(expf(xx));
          }
        }
  }
}

// ---------------- fused final GEMM + epilogue, 512 thr, 64x64 tile, BK=64 --------
// grid 256 = 8 XCD x 32; LDS-aliased fp32 epilogue tile -> 4 blocks/CU (2048 thr)
__global__ __launch_bounds__(512) void gemm_final(const bf16* __restrict__ y, const bf16* __restrict__ tb,
                                                  const bf16* __restrict__ W, const bf16* __restrict__ psum,
                                                  const float* __restrict__ x, const float* __restrict__ pb,
                                                  float* __restrict__ out){
  __shared__ __align__(16) bf16 lds[2][(64+64)*72];
  int orig = blockIdx.x;
  int swz = (orig & 7)*32 + (orig >> 3);   // 256 = 8*32, bijective
  int mt_ = swz & 63, nt_ = swz >> 6;
  int m0 = mt_*64, n0 = nt_*64;
  int t = threadIdx.x;
  int wave = t >> 6, lane = t & 63;
  int lrow = lane & 15, quad = lane >> 4, lk8 = quad*8;
  int wm = (wave & 1)*32, wn = (wave >> 1)*16;

  f32x4_t acc[2];
  acc[0] = (f32x4_t){0,0,0,0}; acc[1] = (f32x4_t){0,0,0,0};

  int rowA = t >> 3, oA = (t & 7)*8;   // 64 rows x 8 col-chunks, 512 threads exactly

  #pragma unroll
  for (int ph = 0; ph < 3; ++ph){
    const bf16 *Ab, *Bb; int lda, ldb, K, rev;
    if (ph == 0){ Ab = y;                             lda = DINNER; K = DINNER; Bb = W;                             ldb = DINNER; rev = 0; }
    else if (ph == 1){ Ab = y + (size_t)M_TOT*DINNER; lda = DINNER; K = DINNER; Bb = W + (size_t)DMODEL*DINNER;     ldb = DINNER; rev = 1; }
    else { Ab = tb; lda = DMODEL; K = DMODEL; Bb = psum; ldb = DMODEL; rev = 0; }

    int am = m0 + rowA;
    if (rev) am = (am & ~(L_SEQ-1)) | ((L_SEQ-1) - (am & (L_SEQ-1)));
    const bf16* Ap = Ab + (size_t)am*lda + oA;
    const bf16* Bp = Bb + (size_t)(n0 + rowA)*ldb + oA;

    int nit = K >> 6;   // 16 or 4, always even
    uint4 au = *(const uint4*)Ap;
    uint4 bu = *(const uint4*)Bp;
    uint4 av = *(const uint4*)(Ap + 64);
    uint4 bv = *(const uint4*)(Bp + 64);

#define FSTAGE(buf, A_, B_) \
    *(uint4*)&lds[buf][rowA*72 + oA] = A_; \
    *(uint4*)&lds[buf][(64 + rowA)*72 + oA] = B_;

#define FCOMP(buf) { \
    const bf16* cs = lds[buf]; \
    _Pragma("unroll") \
    for (int ks = 0; ks < 2; ++ks){ \
      bf16x8_t bq = *(const bf16x8_t*)&cs[(64 + wn + lrow)*72 + ks*32 + lk8]; \
      _Pragma("unroll") \
      for (int mt = 0; mt < 2; ++mt){ \
        bf16x8_t af = *(const bf16x8_t*)&cs[(wm + mt*16 + lrow)*72 + ks*32 + lk8]; \
        acc[mt] = __builtin_amdgcn_mfma_f32_16x16x32_bf16(af, bq, acc[mt], 0, 0, 0); \
      } \
    } }

    __syncthreads();
    FSTAGE(0, au, bu)
    __syncthreads();
    for (int it = 0; it < nit; it += 2){
      if (it + 2 < nit){
        int kk = (it+2) << 6;
        au = *(const uint4*)(Ap+kk); bu = *(const uint4*)(Bp+kk);
      }
      FCOMP(0)
      FSTAGE(1, av, bv)
      __syncthreads();
      if (it + 3 < nit){
        int kk = (it+3) << 6;
        av = *(const uint4*)(Ap+kk); bv = *(const uint4*)(Bp+kk);
      }
      FCOMP(1)
      if (it + 2 < nit){
        FSTAGE(0, au, bu)
        __syncthreads();
      }
    }
#undef FSTAGE
#undef FCOMP
  }

  // epilogue: fp32 tile aliased onto lds buffer 0 (16.6 KB <= 18.4 KB)
  __syncthreads();
  float* tile = (float*)lds;          // [64][65]
  #pragma unroll
  for (int mt = 0; mt < 2; ++mt)
    #pragma unroll
    for (int r = 0; r < 4; ++r)
      tile[(wm + mt*16 + quad*4 + r)*65 + wn + lrow] = acc[mt][r];
  __syncthreads();
  int b = m0 >> 11, l0 = m0 & (L_SEQ-1);
  int tx = t & 63, ny = t >> 6;
  for (int nn = ny; nn < 64; nn += 8){
    int n = n0 + nn;
    size_t xi = (size_t)b*DMODEL*L_SEQ + (size_t)n*L_SEQ + l0 + tx;
    out[xi] = tile[tx*65 + nn] + pb[n] + x[xi];
  }
}

// ---------------- depthwise causal conv + SiLU, vectorized rolling window --------
__global__ __launch_bounds__(256) void k_conv(const bf16* __restrict__ xraw, const float* __restrict__ cw0,
                                              const float* __restrict__ cb0, const float* __restrict__ cw1,
                                              const float* __restrict__ cb1, bf16* __restrict__ xconv){
  int t = threadIdx.x;
  int tx = t & 31, ty = t >> 5;
  int ch0 = blockIdx.x*256 + tx*8;
  int z = blockIdx.z; int b = z & 1, dir = z >> 1;
  int lbase = blockIdx.y*32 + ty*4;
  const float* cw = dir ? cw1 : cw0;
  const float* cb = dir ? cb1 : cb0;
  const bf16* xr = xraw  + (size_t)dir*((size_t)M_TOT*CONVDIM) + (size_t)(b*L_SEQ)*CONVDIM + ch0;
  bf16* xcv      = xconv + (size_t)dir*((size_t)M_TOT*CONVDIM) + (size_t)(b*L_SEQ)*CONVDIM + ch0;

  float wk[4][8];
  #pragma unroll
  for (int c = 0; c < 8; ++c){
    float4 w = *(const float4*)&cw[(ch0+c)*4];
    wk[0][c] = w.x; wk[1][c] = w.y; wk[2][c] = w.z; wk[3][c] = w.w;
  }
  float bias[8];
  {
    float4 b0v = *(const float4*)&cb[ch0];
    float4 b1v = *(const float4*)&cb[ch0+4];
    bias[0]=b0v.x; bias[1]=b0v.y; bias[2]=b0v.z; bias[3]=b0v.w;
    bias[4]=b1v.x; bias[5]=b1v.y; bias[6]=b1v.z; bias[7]=b1v.w;
  }

  bf16x8_t zero;
  #pragma unroll
  for (int c = 0; c < 8; ++c) zero[c] = (__bf16)0.f;

  bf16x8_t win[4];
  #pragma unroll
  for (int k = 0; k < 3; ++k){
    int ls = lbase - 3 + k;
    win[k] = (ls >= 0) ? *(const bf16x8_t*)&xr[(size_t)ls*CONVDIM] : zero;
  }
  #pragma unroll
  for (int i = 0; i < 4; ++i){
    int l = lbase + i;
    win[3] = *(const bf16x8_t*)&xr[(size_t)l*CONVDIM];
    bf16x8_t outv;
    #pragma unroll
    for (int c = 0; c < 8; ++c){
      float a = bias[c] + (float)win[0][c]*wk[0][c] + (float)win[1][c]*wk[1][c]
                        + (float)win[2][c]*wk[2][c] + (float)win[3][c]*wk[3][c];
      outv[c] = (__bf16)(a / (1.f + __expf(-a)));
    }
    *(bf16x8_t*)&xcv[(size_t)l*CONVDIM] = outv;
    win[0] = win[1]; win[1] = win[2]; win[2] = win[3];
  }
}

// ---------------- merged: per-chunk states+scan (0-511) | CB GEMM (512-1023) -----
__global__ __launch_bounds__(256) void k_states_cb(const bf16* __restrict__ xconv, const float* __restrict__ dt,
                                                   const float* __restrict__ Al0, const float* __restrict__ Al1,
                                                   float* __restrict__ A_cs, float* __restrict__ states,
                                                   bf16* __restrict__ CB){
  __shared__ __align__(16) char smem[34816];
  int bz = blockIdx.x, t = threadIdx.x;
  if (bz < 512){
    float* s_acs = (float*)smem;
    float* w_s   = (float*)(smem + 1024);
    __bf16* Xt   = (__bf16*)(smem + 2048);
    __bf16* Bt   = (__bf16*)(smem + 2048 + 9216);
    int id0 = bz;
    int dir = id0 >> 8; int id = id0 & 255;
    int h = id & 15; int bc = id >> 4; int ch = bc & 7; int b = bc >> 3;
    const bf16* xc = xconv + (size_t)dir*((size_t)M_TOT*CONVDIM);
    const float* dtp = dt + (size_t)dir*((size_t)M_TOT*NH);
    const float* Alog = dir ? Al1 : Al0;
    size_t rowbase = (size_t)(b*L_SEQ) + ch*CT;

    float dtv = dtp[(rowbase + t)*NH + h];
    s_acs[t] = -expf(Alog[h]) * dtv;
    __syncthreads();
    for (int off = 1; off < 256; off <<= 1){
      float v = (t >= off) ? s_acs[t-off] : 0.f;
      __syncthreads();
      s_acs[t] += v;
      __syncthreads();
    }
    A_cs[(size_t)dir*ACS_N + (size_t)((b*NH+h)*NCHK + ch)*CT + t] = s_acs[t];
    float alast = s_acs[CT-1];
    w_s[t] = dtv * __expf(fminf(alast - s_acs[t], 0.f));
    __syncthreads();

    int wave = t >> 6, lane = t & 63, lrow = lane & 15, quad = lane >> 4;
    f32x4_t acc[8];
    #pragma unroll
    for (int i = 0; i < 8; ++i) acc[i] = (f32x4_t){0.f,0.f,0.f,0.f};

    for (int kt = 0; kt < 4; ++kt){
      int l0 = kt*64;
      #pragma unroll
      for (int it = 0; it < 2; ++it){
        int idx = t + it*256; int l = idx >> 3; int p0 = (idx & 7)*8;
        bf16x8_t v = *(const bf16x8_t*)&xc[(rowbase + l0 + l)*CONVDIM + h*HD + p0];
        float w = w_s[l0 + l];
        int col = (((l>>3) ^ ((p0>>3)&7))<<3) | (l&7);
        #pragma unroll
        for (int j = 0; j < 8; ++j) Xt[(p0+j)*72 + col] = (__bf16)((float)v[j]*w);
      }
      #pragma unroll
      for (int it = 0; it < 4; ++it){
        int idx = t + it*256; int l = idx >> 4; int n0 = (idx & 15)*8;
        bf16x8_t v = *(const bf16x8_t*)&xc[(rowbase + l0 + l)*CONVDIM + DINNER + n0];
        int col = (((l>>3) ^ ((n0>>3)&7))<<3) | (l&7);
        #pragma unroll
        for (int j = 0; j < 8; ++j) Bt[(n0+j)*72 + col] = v[j];
      }
      __syncthreads();
      int arow = wave*16 + lrow;
      #pragma unroll
      for (int ks = 0; ks < 2; ++ks){
        int kg = ks*4 + quad;
        bf16x8_t af = *(const bf16x8_t*)&Xt[arow*72 + ((kg ^ ((arow>>3)&7))<<3)];
        #pragma unroll
        for (int nt = 0; nt < 8; ++nt){
          int brow = nt*16 + lrow;
          bf16x8_t bq = *(const bf16x8_t*)&Bt[brow*72 + ((kg ^ ((brow>>3)&7))<<3)];
          acc[nt] = __builtin_amdgcn_mfma_f32_16x16x32_bf16(af, bq, acc[nt], 0, 0, 0);
        }
      }
      __syncthreads();
    }
    float* so = states + (size_t)dir*ST_N + (size_t)id*HD*DSTATE;
    int m = wave*16 + quad*4;
    #pragma unroll
    for (int nt = 0; nt < 8; ++nt)
      #pragma unroll
      for (int r = 0; r < 4; ++r)
        so[(size_t)(m+r)*DSTATE + nt*16 + lrow] = acc[nt][r];
  } else {
    __bf16* As = (__bf16*)smem;
    __bf16* Bs = (__bf16*)(smem + 17408);
    int sub = bz - 512;
    int zz = sub >> 4;
    int dir = zz >> 4; int b = (zz >> 3) & 1; int ch = zz & 7;
    int rest = sub & 15;
    int m0 = (rest >> 2)*64, n0 = (rest & 3)*64;
    if (n0 > m0) return;
    const bf16* base = xconv + (size_t)dir*((size_t)M_TOT*CONVDIM) + (size_t)(b*L_SEQ + ch*CT)*CONVDIM;
    const bf16* Crow = base + DINNER + DSTATE;
    const bf16* Brow = base + DINNER;
    int r = t >> 2, o0 = (t & 3)*32;
    #pragma unroll
    for (int j = 0; j < 4; ++j){
      *(bf16x8_t*)&As[r*136 + o0 + j*8] = *(const bf16x8_t*)&Crow[(size_t)(m0+r)*CONVDIM + o0 + j*8];
      *(bf16x8_t*)&Bs[r*136 + o0 + j*8] = *(const bf16x8_t*)&Brow[(size_t)(n0+r)*CONVDIM + o0 + j*8];
    }
    __syncthreads();
    int wave = t >> 6, lane = t & 63, lrow = lane & 15, quad = lane >> 4;
    int wm = wave*16;
    f32x4_t acc[4];
    #pragma unroll
    for (int i = 0; i < 4; ++i) acc[i] = (f32x4_t){0.f,0.f,0.f,0.f};
    #pragma unroll
    for (int ks = 0; ks < 4; ++ks){
      bf16x8_t af = *(const bf16x8_t*)&As[(wm+lrow)*136 + ks*32 + quad*8];
      #pragma unroll
      for (int nt = 0; nt < 4; ++nt){
        bf16x8_t bq = *(const bf16x8_t*)&Bs[(nt*16+lrow)*136 + ks*32 + quad*8];
        acc[nt] = __builtin_amdgcn_mfma_f32_16x16x32_bf16(af, bq, acc[nt], 0, 0, 0);
      }
    }
    __syncthreads();
    #pragma unroll
    for (int nt = 0; nt < 4; ++nt)
      #pragma unroll
      for (int r2 = 0; r2 < 4; ++r2)
        As[(wm + quad*4 + r2)*72 + nt*16 + lrow] = (__bf16)acc[nt][r2];
    __syncthreads();
    bf16* outp = CB + (size_t)dir*CB_N + (size_t)(b*NCHK+ch)*CT*CT;
    #pragma unroll
    for (int p = 0; p < 2; ++p){
      int idx = t + p*256;
      int row = idx >> 3, c8 = (idx & 7)*8;
      *(bf16x8_t*)&outp[(size_t)(m0+row)*CT + n0 + c8] = *(const bf16x8_t*)&As[row*72 + c8];
    }
  }
}

// ---------------- inter-chunk recurrence: emits bf16 prefix states ---------------
__global__ __launch_bounds__(256) void k_recur(const float* __restrict__ states, bf16* __restrict__ nsb,
                                               const float* __restrict__ A_cs){
  int blk = blockIdx.x;
  int bh2 = blk >> 5;
  int e = (blk & 31)*256 + threadIdx.x;
  int dir = bh2 >> 5; int bh = bh2 & 31;
  int h = bh & 15, b = bh >> 4;
  const float* ac = A_cs + (size_t)dir*ACS_N;
  const float* st = states + (size_t)dir*ST_N;
  bf16* nb = nsb + (size_t)dir*ST_N;
  float s = 0.f;
  #pragma unroll
  for (int ch = 0; ch < NCHK; ++ch){
    float dec = expdec(ac[((size_t)(bh*NCHK+ch))*CT + CT-1]);
    size_t off = (size_t)(((b*NCHK+ch)*NH)+h)*HD*DSTATE + e;
    float cur = st[off];
    nb[off] = tob(s);
    s = s*dec + cur;
  }
}

// ---------------- Y = (L*CB)@X + exp(Acs)*(C@NS)  (MFMA, merged-hh 512 thr) ------
__global__ __launch_bounds__(512) void k_y_mfma(const bf16* __restrict__ xconv, const float* __restrict__ dt,
                                                const float* __restrict__ A_cs, const bf16* __restrict__ CB,
                                                const bf16* __restrict__ ns, bf16* __restrict__ y){
  int id0 = blockIdx.x;
  int dir = id0 >> 8; int id = id0 & 255;
  int h = id & 15; int bc = id >> 4; int ch = bc & 7; int b = bc >> 3;
  int t = threadIdx.x;
  int lane = t & 63;
  int lrow = lane & 15, quad = lane >> 4;

  __shared__ __align__(16) bf16 Xs[64*264];
  __shared__ __align__(16) bf16 NSs[64*136];
  __shared__ float acs_s[CT];

  const bf16* xc = xconv + (size_t)dir*((size_t)M_TOT*CONVDIM);
  const float* dtp = dt + (size_t)dir*((size_t)M_TOT*NH);
  const float* acs = A_cs + (size_t)dir*ACS_N + (size_t)((b*NH+h)*NCHK + ch)*CT;
  const bf16* cbz = CB + (size_t)dir*CB_N + (size_t)(b*NCHK+ch)*CT*CT;
  const bf16* nsp = ns + (size_t)dir*ST_N + (size_t)(((b*NCHK+ch)*NH)+h)*HD*DSTATE;
  bf16* yp = y + (size_t)dir*((size_t)M_TOT*DINNER);
  size_t rowbase = (size_t)(b*L_SEQ + ch*CT);
  if (t < CT) acs_s[t] = acs[t];

  #pragma unroll
  for (int it = 0; it < 4; ++it){
    int idx = t + it*512;
    int s = idx >> 3, p0 = (idx & 7)*8;
    float dtv = dtp[(rowbase + s)*NH + h];
    bf16x8_t v = *(const bf16x8_t*)&xc[(rowbase + s)*CONVDIM + h*HD + p0];
    int col = ((((s>>3) ^ ((p0>>3)&7)))<<3) | (s&7);
    #pragma unroll
    for (int j = 0; j < 8; ++j)
      Xs[(p0+j)*264 + col] = tob((float)v[j] * dtv);
  }
  #pragma unroll
  for (int it = 0; it < 2; ++it){
    int idx = t + it*512;
    int p = idx >> 4, n8 = (idx & 15)*8;
    *(bf16x8_t*)&NSs[p*136 + n8] = *(const bf16x8_t*)&nsp[(size_t)p*DSTATE + n8];
  }
  __syncthreads();

  int wave = t >> 6;           // [0,8)
  int row0 = wave*32;
  float al0 = acs_s[row0 + lrow];
  float al1 = acs_s[row0 + 16 + lrow];
  float acs_r0 = acs_s[row0];

  f32x4_t acc[2][4];
  #pragma unroll
  for (int i = 0; i < 2; ++i)
    #pragma unroll
    for (int j = 0; j < 4; ++j) acc[i][j] = (f32x4_t){0.f,0.f,0.f,0.f};

  int nst = (row0 + 32) >> 5;
  for (int st = 0; st < nst; ++st){
    int s0 = st*32;
    if (s0 + 31 < row0 && (acs_r0 - acs_s[s0+31]) < -30.f) continue;
    int sg = (s0 >> 3) + quad;
    bf16x8_t bq[4];
    #pragma unroll
    for (int nt = 0; nt < 4; ++nt){
      int brow = nt*16 + lrow;
      bq[nt] = *(const bf16x8_t*)&Xs[brow*264 + ((sg ^ ((brow>>3)&7))<<3)];
    }
    bf16x8_t af[2];
    #pragma unroll
    for (int mt = 0; mt < 2; ++mt){
      int l = row0 + mt*16 + lrow;
      float al = mt ? al1 : al0;
      bf16x8_t cvv = *(const bf16x8_t*)&cbz[(size_t)l*CT + s0 + quad*8];
      union { bf16x8_t v; __bf16 e[8]; } wa;
      #pragma unroll
      for (int j = 0; j < 8; ++j){
        int s = s0 + quad*8 + j;
        float w = (s <= l) ? __expf(fminf(al - acs_s[s], 0.f)) * (float)cvv[j] : 0.f;
        wa.e[j] = (__bf16)w;
      }
      af[mt] = wa.v;
    }
    #pragma unroll
    for (int mt = 0; mt < 2; ++mt)
      #pragma unroll
      for (int nt = 0; nt < 4; ++nt)
        acc[mt][nt] = __builtin_amdgcn_mfma_f32_16x16x32_bf16(af[mt], bq[nt], acc[mt][nt], 0, 0, 0);
  }

  float el0 = __expf(fminf(al0, 0.f));
  float el1 = __expf(fminf(al1, 0.f));
  #pragma unroll
  for (int kt = 0; kt < 4; ++kt){
    int n0 = kt*32;
    bf16x8_t bq[4];
    #pragma unroll
    for (int nt = 0; nt < 4; ++nt)
      bq[nt] = *(const bf16x8_t*)&NSs[(nt*16+lrow)*136 + n0 + quad*8];
    bf16x8_t af[2];
    #pragma unroll
    for (int mt = 0; mt < 2; ++mt){
      int l = row0 + mt*16 + lrow;
      float el = mt ? el1 : el0;
      union { bf16x8_t v; __bf16 e[8]; } cu;
      cu.v = *(const bf16x8_t*)&xc[(rowbase + l)*CONVDIM + DINNER + DSTATE + n0 + quad*8];
      union { bf16x8_t v; __bf16 e[8]; } wa;
      #pragma unroll
      for (int j = 0; j < 8; ++j) wa.e[j] = (__bf16)((float)cu.e[j] * el);
      af[mt] = wa.v;
    }
    #pragma unroll
    for (int mt = 0; mt < 2; ++mt)
      #pragma unroll
      for (int nt = 0; nt < 4; ++nt)
        acc[mt][nt] = __builtin_amdgcn_mfma_f32_16x16x32_bf16(af[mt], bq[nt], acc[mt][nt], 0, 0, 0);
  }

  #pragma unroll
  for (int mt = 0; mt < 2; ++mt)
    #pragma unroll
    for (int nt = 0; nt < 4; ++nt)
      #pragma unroll
      for (int rr = 0; rr < 4; ++rr){
        int l = row0 + mt*16 + quad*4 + rr;
        int p = nt*16 + lrow;
        yp[(rowbase + l)*DINNER + h*HD + p] = tob(acc[mt][nt][rr]);
      }
}

// ---------------- gate ((y + D*x) * silu(z)) + RMSNorm, vectorized ---------------
__global__ __launch_bounds__(256) void k_gaterms(const bf16* __restrict__ z, const float* __restrict__ nw0,
                                                 const float* __restrict__ nw1, const bf16* __restrict__ xconv,
                                                 const float* __restrict__ Dh0, const float* __restrict__ Dh1,
                                                 bf16* __restrict__ y){
  int m0 = blockIdx.x;
  int dir = m0 >> 12; int m = m0 & (M_TOT-1);
  int t = threadIdx.x;
  const float* nw = dir ? nw1 : nw0;
  const float* Dh = dir ? Dh1 : Dh0;
  int j0 = t*4;
  const bf16* zp = z + (size_t)dir*((size_t)M_TOT*DINNER) + (size_t)m*DINNER;
  const bf16* xc = xconv + (size_t)dir*((size_t)M_TOT*CONVDIM) + (size_t)m*CONVDIM;
  bf16* yp = y + (size_t)dir*((size_t)M_TOT*DINNER) + (size_t)m*DINNER;

  bf16x4_t zv = *(const bf16x4_t*)&zp[j0];
  bf16x4_t yv = *(const bf16x4_t*)&yp[j0];
  bf16x4_t xv = *(const bf16x4_t*)&xc[j0];
  float Dv = Dh[j0 >> 6];
  float v[4]; float ss = 0.f;
  #pragma unroll
  for (int c = 0; c < 4; ++c){
    float zf = (float)zv[c];
    float raw = (float)yv[c] + Dv*(float)xv[c];
    float g = raw * (zf / (1.f + __expf(-zf)));
    v[c] = g; ss += g*g;
  }
  for (int o = 32; o > 0; o >>= 1) ss += __shfl_down(ss, o, 64);
  __shared__ float sh[4];
  if ((t & 63) == 0) sh[t>>6] = ss;
  __syncthreads();
  ss = sh[0]+sh[1]+sh[2]+sh[3];
  float scale = rsqrtf(ss*(1.f/DINNER) + 1e-5f);
  float4 nwv = *(const float4*)&nw[j0];
  float nws[4] = {nwv.x, nwv.y, nwv.z, nwv.w};
  bf16x4_t o;
  #pragma unroll
  for (int c = 0; c < 4; ++c) o[c] = (__bf16)(v[c]*scale*nws[c]);
  *(bf16x4_t*)&yp[j0] = o;
}

extern "C" void kernel_launch(void* const* d_in, const int* in_sizes, int n_in,
                              void* d_out, int out_size, void* d_ws, size_t ws_size,
                              hipStream_t stream){
  (void)in_sizes; (void)n_in; (void)out_size; (void)ws_size;
  const float* x      = (const float*)d_in[0];
  const float* gn_w   = (const float*)d_in[1];
  const float* gn_b   = (const float*)d_in[2];
  const float* proj_w = (const float*)d_in[3];
  const float* proj_b = (const float*)d_in[4];
  float* out = (float*)d_out;

  char* wp = (char*)d_ws;
  auto alloc = [&](size_t bytes){ void* r = (void*)wp; wp += (bytes + 255) & ~(size_t)255; return r; };
  bf16*  t_buf  = (bf16*) alloc((size_t)M_TOT*DMODEL*2);
  bf16*  z_buf  = (bf16*) alloc((size_t)2*M_TOT*DINNER*2);
  bf16*  xraw   = (bf16*) alloc((size_t)2*M_TOT*CONVDIM*2);   // reused as y (both dirs)
  bf16*  xconv  = (bf16*) alloc((size_t)2*M_TOT*CONVDIM*2);
  float* dt_buf = (float*)alloc((size_t)2*M_TOT*NH*4);
  float* acs    = (float*)alloc((size_t)2*ACS_N*4);
  float* states = (float*)alloc((size_t)2*ST_N*4);
  bf16*  nsb    = (bf16*) alloc((size_t)2*ST_N*2);
  bf16*  cb     = (bf16*) alloc((size_t)2*CB_N*2);
  float2* pbuf  = (float2*)alloc(BATCH*128*sizeof(float2));
  bf16*  inw_bf   = (bf16*)alloc((size_t)2*DPROJ*DMODEL*2);
  bf16*  projw_bf = (bf16*)alloc((size_t)DMODEL*2*DMODEL*2);
  bf16*  owt      = (bf16*)alloc((size_t)2*DINNER*DMODEL*2);
  bf16*  wfb      = (bf16*)alloc((size_t)2*DMODEL*DINNER*2);
  bf16*  psum     = (bf16*)alloc((size_t)DMODEL*DMODEL*2);
  bf16*  y_buf    = xraw;   // xraw dead after conv

  k_front<<<1704, 256, 0, stream>>>(
      (const float*)d_in[5], (const float*)d_in[13], proj_w,
      inw_bf, projw_bf,
      (const float*)d_in[12], (const float*)d_in[20], owt, psum,
      x, pbuf);

  k_wt<<<320, 256, 0, stream>>>(projw_bf, owt, wfb, x, gn_w, gn_b, pbuf, t_buf);

  gemm_inproj<<<dim3(608, 1, 2), 512, 0, stream>>>(
      t_buf, inw_bf, z_buf, xraw, dt_buf,
      (const float*)d_in[8], (const float*)d_in[16]);

  k_conv<<<dim3(5, L_SEQ/32, 2*BATCH), 256, 0, stream>>>(
      xraw, (const float*)d_in[6], (const float*)d_in[7],
            (const float*)d_in[14], (const float*)d_in[15], xconv);
  k_states_cb<<<1024, 256, 0, stream>>>(
      xconv, dt_buf, (const float*)d_in[9], (const float*)d_in[17], acs, states, cb);
  k_recur<<<2*BATCH*NH*32, 256, 0, stream>>>(states, nsb, acs);
  k_y_mfma<<<2*BATCH*NCHK*NH, 512, 0, stream>>>(xconv, dt_buf, acs, cb, nsb, y_buf);
  k_gaterms<<<2*M_TOT, 256, 0, stream>>>(
      z_buf, (const float*)d_in[11], (const float*)d_in[19], xconv,
      (const float*)d_in[10], (const float*)d_in[18], y_buf);

  gemm_final<<<256, 512, 0, stream>>>(y_buf, t_buf, wfb, psum, x, proj_b, out);
}